// Round 10
// baseline (1169.853 us; speedup 1.0000x reference)
//
#include <hip/hip_runtime.h>
#include <math.h>

#define EE 819200          // edges total
#define BGRAPH 8192        // graphs
constexpr int GT = 512;    // threads, graph kernel (8 waves, 2 halves)

typedef __attribute__((ext_vector_type(8))) short bf16x8;   // 4 VGPRs = 8 bf16
typedef __attribute__((ext_vector_type(4))) float f32x4;

// ---- fp32 -> bf16 split (RNE), a ~= hi + lo, |a-(hi+lo)| <= 2^-18 |a| ----
__device__ inline unsigned short f2bf(float x) {
    unsigned u = __float_as_uint(x);
    u += 0x7fffu + ((u >> 16) & 1u);
    return (unsigned short)(u >> 16);
}
__device__ inline float bf2f(unsigned short h) {
    return __uint_as_float(((unsigned)h) << 16);
}
__device__ inline void split2(float v, unsigned short& hi, unsigned short& lo) {
    hi = f2bf(v);
    lo = f2bf(v - bf2f(hi));
}
// packed RNE split of a value-pair: h = {bf16(b)|bf16(a)}, l = residuals
__device__ inline unsigned cvtpk_bf16(float a, float b) {
    unsigned r;
    asm("v_cvt_pk_bf16_f32 %0, %1, %2" : "=v"(r) : "v"(a), "v"(b));
    return r;
}
__device__ inline void split_pair(float a, float b, unsigned& h, unsigned& l) {
    h = cvtpk_bf16(a, b);
    const float ra = a - __uint_as_float(h << 16);
    const float rb = b - __uint_as_float(h & 0xffff0000u);
    l = cvtpk_bf16(ra, rb);
}

// ---------------------------------------------------------------------------
// Fused weight prep (one launch): W[K][N] fp32 -> fragment-ordered hi/lo bf16,
// zero-padded to (KS*32) x (NT*16).
// ---------------------------------------------------------------------------
struct WDesc { const float* W; unsigned short* Bh; unsigned short* Bl;
               int K, N, KS, NT, base; };
struct WTab { WDesc d[11]; };

__global__ __launch_bounds__(256) void wprep_all(WTab tab)
{
    const int bid = blockIdx.x;
    int t = 0;
#pragma unroll
    for (int i = 1; i < 11; ++i) if (bid >= tab.d[i].base) t = i;
    const WDesc D = tab.d[t];
    const int idx = (bid - D.base) * 256 + (int)threadIdx.x;
    if (idx >= D.NT * D.KS * 512) return;
    const int r    = idx & 7;
    const int lane = (idx >> 3) & 63;
    const int rest = idx >> 9;
    const int ks   = rest % D.KS;
    const int nt   = rest / D.KS;
    const int k = ks * 32 + ((lane >> 4) << 3) + r;
    const int n = nt * 16 + (lane & 15);
    const float v = (k < D.K && n < D.N) ? D.W[(size_t)k * D.N + n] : 0.f;
    unsigned short h, l; split2(v, h, l);
    D.Bh[idx] = h; D.Bl[idx] = l;
}

// ---------------------------------------------------------------------------
// 2-graphs-per-block GCN: waves 0-3 = graph A, waves 4-7 = graph B, with B's
// pipeline one slot behind A's -> every slot pairs agg(VALU) with MFMA(matrix)
// on different halves. Each half: 4 waves, wave wh owns n-tiles wh+4i, all 4
// m-tiles (rows 0-63). Frags [50][168] hi/lo per graph in one flat fragbuf
// (trailing extent absorbs the rows-50..63 MFMA overread; those D-rows are
// discarded by row<50 guards). k-cols 80..95 zeroed (NaN safety, L1/L2).
// ---------------------------------------------------------------------------

template<int KS, int NI, int FOUT>
__device__ inline void layer_half(const unsigned short* __restrict__ Bh,
                                  const unsigned short* __restrict__ Bl,
                                  const unsigned short* Ah, const unsigned short* Al,
                                  f32x4 (&acc)[4][5], int wh, int lane)
{
#pragma unroll
    for (int m = 0; m < 4; ++m)
#pragma unroll
        for (int i = 0; i < NI; ++i) acc[m][i] = (f32x4){0.f, 0.f, 0.f, 0.f};
    const int l15 = lane & 15;
    const int g8 = (lane >> 4) << 3;
    const int l8 = lane << 3;
#pragma unroll
    for (int ks = 0; ks < KS; ++ks) {
        bf16x8 ah[4], al[4];
#pragma unroll
        for (int m = 0; m < 4; ++m) {
            const int off = (m * 16 + l15) * 168 + ks * 32 + g8;
            ah[m] = *(const bf16x8*)(Ah + off);
            al[m] = *(const bf16x8*)(Al + off);
        }
#pragma unroll
        for (int i = 0; i < NI; ++i) {
            const int nt = wh + (i << 2);
            if (nt * 16 < FOUT) {              // skip all-zero W tiles (uniform)
                const int bo = ((nt * KS + ks) << 9) + l8;
                const bf16x8 bh = *(const bf16x8*)(Bh + bo);
                const bf16x8 bl = *(const bf16x8*)(Bl + bo);
#pragma unroll
                for (int m = 0; m < 4; ++m) {
                    acc[m][i] = __builtin_amdgcn_mfma_f32_16x16x32_bf16(ah[m], bh, acc[m][i], 0, 0, 0);
                    acc[m][i] = __builtin_amdgcn_mfma_f32_16x16x32_bf16(al[m], bh, acc[m][i], 0, 0, 0);
                    acc[m][i] = __builtin_amdgcn_mfma_f32_16x16x32_bf16(ah[m], bl, acc[m][i], 0, 0, 0);
                }
            }
        }
    }
}

// D layout: col = lane&15 (+16*nt), row = (lane>>4)*4 + reg (+16*m)
template<int NI, int NCOL>
__device__ inline void epi_half(const f32x4 (&acc)[4][5], const float* __restrict__ bias,
                                float* act, int wh, int lane)
{
    const int l15 = lane & 15, g4 = (lane >> 4) << 2;
#pragma unroll
    for (int i = 0; i < NI; ++i) {
        const int col = (wh + (i << 2)) * 16 + l15;
        if (col < NCOL) {
            const float bj = bias[col];
#pragma unroll
            for (int m = 0; m < 4; ++m)
#pragma unroll
                for (int r = 0; r < 4; ++r) {
                    const int row = m * 16 + g4 + r;
                    if (row < 50)
                        act[row * 160 + col] = fmaxf(acc[m][i][r] + bj, 0.f);
                }
        }
    }
}

__device__ inline void pool_half(const f32x4 (&acc)[4][5], const float* __restrict__ bias,
                                 unsigned* gmax, int wh, int lane)
{
    const int l15 = lane & 15, g4 = (lane >> 4) << 2;
#pragma unroll
    for (int i = 0; i < 5; ++i) {
        const int col = (wh + (i << 2)) * 16 + l15;
        const float bj = (col < 312) ? bias[col] : 0.f;
        float m = 0.f;                      // relu floor == pool identity
#pragma unroll
        for (int mm = 0; mm < 4; ++mm)
#pragma unroll
            for (int r = 0; r < 4; ++r) {
                const int row = mm * 16 + g4 + r;
                if (row < 50) m = fmaxf(m, acc[mm][i][r] + bj);
            }
        m = fmaxf(m, __shfl_xor(m, 16, 64));
        m = fmaxf(m, __shfl_xor(m, 32, 64));
        if (lane < 16 && col < 312)
            atomicMax(&gmax[col], __float_as_uint(m));
    }
}

// agg (Â·H) fused with bf16-split, 8 features/item, 256 threads per half.
template<int NCOL>
__device__ inline void agg_half(const float4* __restrict__ act4,
                                unsigned short* Ah, unsigned short* Al,
                                const int* insrc, const float* insn,
                                const int* inoff, const float* selfw, int ht)
{
    constexpr int CH = (NCOL + 7) / 8;     // 8-float chunks per row (pads zero)
    for (int idx = ht; idx < 50 * CH; idx += 256) {
        const int n = idx / CH;            // constexpr divisor -> magic-mul
        const int c2 = (idx - n * CH) * 2; // float4 index within row
        const float sw = selfw[n];
        const float4 v0 = act4[n * 40 + c2];
        const float4 v1 = act4[n * 40 + c2 + 1];
        float4 a0, a1;
        a0.x = sw * v0.x; a0.y = sw * v0.y; a0.z = sw * v0.z; a0.w = sw * v0.w;
        a1.x = sw * v1.x; a1.y = sw * v1.y; a1.z = sw * v1.z; a1.w = sw * v1.w;
        int j = inoff[n];
        const int j1 = inoff[n + 1];
        for (; j + 1 < j1; j += 2) {
            const int s0 = insrc[j] * 40 + c2;
            const int s1 = insrc[j + 1] * 40 + c2;
            const float w0 = insn[j], w1 = insn[j + 1];
            const float4 e00 = act4[s0], e01 = act4[s0 + 1];
            const float4 e10 = act4[s1], e11 = act4[s1 + 1];
            a0.x = fmaf(w1, e10.x, fmaf(w0, e00.x, a0.x));
            a0.y = fmaf(w1, e10.y, fmaf(w0, e00.y, a0.y));
            a0.z = fmaf(w1, e10.z, fmaf(w0, e00.z, a0.z));
            a0.w = fmaf(w1, e10.w, fmaf(w0, e00.w, a0.w));
            a1.x = fmaf(w1, e11.x, fmaf(w0, e01.x, a1.x));
            a1.y = fmaf(w1, e11.y, fmaf(w0, e01.y, a1.y));
            a1.z = fmaf(w1, e11.z, fmaf(w0, e01.z, a1.z));
            a1.w = fmaf(w1, e11.w, fmaf(w0, e01.w, a1.w));
        }
        if (j < j1) {
            const int s0 = insrc[j] * 40 + c2;
            const float w0 = insn[j];
            const float4 e00 = act4[s0], e01 = act4[s0 + 1];
            a0.x = fmaf(w0, e00.x, a0.x);
            a0.y = fmaf(w0, e00.y, a0.y);
            a0.z = fmaf(w0, e00.z, a0.z);
            a0.w = fmaf(w0, e00.w, a0.w);
            a1.x = fmaf(w0, e01.x, a1.x);
            a1.y = fmaf(w0, e01.y, a1.y);
            a1.z = fmaf(w0, e01.z, a1.z);
            a1.w = fmaf(w0, e01.w, a1.w);
        }
        unsigned h01, h23, h45, h67, l01, l23, l45, l67;
        split_pair(a0.x, a0.y, h01, l01);
        split_pair(a0.z, a0.w, h23, l23);
        split_pair(a1.x, a1.y, h45, l45);
        split_pair(a1.z, a1.w, h67, l67);
        const int off = n * 168 + (c2 << 2);           // 16B-aligned
        *(uint4*)(Ah + off) = make_uint4(h01, h23, h45, h67);
        *(uint4*)(Al + off) = make_uint4(l01, l23, l45, l67);
    }
}

__global__ __launch_bounds__(GT) void gcn_graph2(
    const float* __restrict__ x1, const int* __restrict__ ei1,
    const float* __restrict__ x2, const int* __restrict__ ei2,
    const unsigned short* __restrict__ W1h, const unsigned short* __restrict__ W1l,
    const unsigned short* __restrict__ W2h, const unsigned short* __restrict__ W2l,
    const unsigned short* __restrict__ W3h, const unsigned short* __restrict__ W3l,
    const float* __restrict__ bc1, const float* __restrict__ bc2, const float* __restrict__ bc3,
    float* __restrict__ G)              // [2*B,312]
{
    // flat frag storage: Ah0@0 Al0@8400 Ah1@16800 Al1@25200; trailing extent
    // absorbs rows-50..63 overreads (max idx 25200+10744)
    __shared__ __align__(16) unsigned short fragbuf[35944];
    __shared__ float4 act4s[2][50 * 40];               // fp32 act [50][160] x2
    __shared__ int   es[2][100], ed[2][100], insrc[2][100];
    __shared__ float insn[2][100];
    __shared__ int   inoff[2][51], cnt[2][50], cnt2[2][50];
    __shared__ float dinvs[2][50], selfw[2][50];
    __shared__ unsigned gmax[2][312];

    const int tid = threadIdx.x;
    const int h   = tid >> 8;              // half: 0 = graph A, 1 = graph B
    const int ht  = tid & 255;
    const int wh  = (tid >> 6) & 3;        // wave within half
    const int lane = tid & 63;

    const int g  = blockIdx.x * 2 + h;     // combined graph index [0,16384)
    const int br = g >> 13;
    const int b  = g & (BGRAPH - 1);
    const float* X    = br ? x2 : x1;
    const int*   srcA = br ? ei2 : ei1;
    const int*   dstA = srcA + EE;
    const int nb = b * 50, eb = b * 100;

    unsigned short* Ah = fragbuf + h * 16800;
    unsigned short* Al = Ah + 8400;
    float* act = (float*)act4s[h];
    const float4* act4 = act4s[h];

    // ---- prologue (each half builds its own graph state; barriers shared)
    for (int i = ht; i < 400; i += 256) {          // frag k-band 80..95 zero
        const int n = i >> 3, c = ((i & 7) << 1) + 80;
        *(unsigned*)(Ah + n * 168 + c) = 0u;
        *(unsigned*)(Al + n * 168 + c) = 0u;
    }
    for (int i = ht; i < 300; i += 256) {          // act pad cols zero
        const int n = i / 6, j = i - 6 * n;
        act[n * 160 + (j < 2 ? 78 + j : 154 + j)] = 0.f;
    }
    for (int i = ht; i < 312; i += 256) gmax[h][i] = 0u;
    for (int i = ht; i < 50; i += 256) { cnt[h][i] = 0; cnt2[h][i] = 0; }
    for (int e = ht; e < 100; e += 256) { es[h][e] = srcA[eb + e] - nb; ed[h][e] = dstA[eb + e] - nb; }
    for (int idx = ht; idx < 3900; idx += 256) {   // X staging (coalesced)
        const int n = idx / 78, c = idx - n * 78;
        act[n * 160 + c] = X[(size_t)nb * 78 + idx];
    }
    __syncthreads();
    for (int e = ht; e < 100; e += 256) atomicAdd(&cnt[h][ed[h][e]], 1);
    __syncthreads();
    for (int n = ht; n < 50; n += 256) {
        const float dv = 1.0f / sqrtf((float)cnt[h][n] + 1.0f);
        dinvs[h][n] = dv; selfw[h][n] = dv * dv;
    }
    if (ht == 0) {                                  // per-half serial prefix
        int off = 0;
        for (int n = 0; n < 50; ++n) { inoff[h][n] = off; off += cnt[h][n]; }
        inoff[h][50] = off;
    }
    __syncthreads();
    for (int e = ht; e < 100; e += 256) {          // counting-sort by dst
        const int d = ed[h][e];
        const int p = inoff[h][d] + atomicAdd(&cnt2[h][d], 1);
        insrc[h][p] = es[h][e];
        insn[h][p]  = dinvs[h][es[h][e]] * dinvs[h][d];
    }
    __syncthreads();

    f32x4 acc[4][5];

    auto AGG1 = [&] { agg_half<78 >(act4, Ah, Al, insrc[h], insn[h], inoff[h], selfw[h], ht); };
    auto AGG3 = [&] { agg_half<156>(act4, Ah, Al, insrc[h], insn[h], inoff[h], selfw[h], ht); };
    auto MF1 = [&] {
        __builtin_amdgcn_s_setprio(1);
        layer_half<3, 2, 78>(W1h, W1l, Ah, Al, acc, wh, lane);
        __builtin_amdgcn_s_setprio(0);
        epi_half<2, 78>(acc, bc1, act, wh, lane);
    };
    auto MF2 = [&] {
        __builtin_amdgcn_s_setprio(1);
        layer_half<3, 3, 156>(W2h, W2l, Ah, Al, acc, wh, lane);
        __builtin_amdgcn_s_setprio(0);
        epi_half<3, 156>(acc, bc2, act, wh, lane);
    };
    auto MF3 = [&] {
        __builtin_amdgcn_s_setprio(1);
        layer_half<5, 5, 312>(W3h, W3l, Ah, Al, acc, wh, lane);
        __builtin_amdgcn_s_setprio(0);
        pool_half(acc, bc3, gmax[h], wh, lane);
    };
    auto STG = [&] {
        for (int f = ht; f < 312; f += 256)
            G[(size_t)g * 312 + f] = __uint_as_float(gmax[h][f]);
    };

    // ---- phase-offset slots: half 1 runs one slot behind half 0, so each
    // slot mixes VALU agg (one half) with MFMA (the other half).
    if (h == 0) AGG1();
    __syncthreads();
    if (h == 0) MF1(); else AGG1();     // agg L2 == agg L1 (same NCOL=78)
    __syncthreads();
    if (h == 0) AGG1(); else MF1();
    __syncthreads();
    if (h == 0) MF2(); else AGG1();
    __syncthreads();
    if (h == 0) AGG3(); else MF2();
    __syncthreads();
    if (h == 0) MF3(); else AGG3();
    __syncthreads();
    if (h == 0) STG(); else MF3();
    __syncthreads();
    if (h == 1) STG();
}

// ---------------------------------------------------------------------------
// Dense bf16x3 MFMA GEMM (unfused form, used for Wr2/Wr3).
// ---------------------------------------------------------------------------
template<int NTW, bool RELU>
__global__ __launch_bounds__(256) void gemm_dense(
    const float* __restrict__ A, int lda, int K, int KS,
    const unsigned short* __restrict__ Bh, const unsigned short* __restrict__ Bl,
    const float* __restrict__ bias, int Nout,
    float* __restrict__ C, int ldc, int coff)
{
    __shared__ unsigned short Ahs[64 * 40], Als[64 * 40];
    const int tid = threadIdx.x, lane = tid & 63, w = tid >> 6;
    const int bm = blockIdx.x * 64;
    const int ntb = blockIdx.y * 4 * NTW;
    f32x4 acc[4][NTW];
#pragma unroll
    for (int m = 0; m < 4; ++m)
#pragma unroll
        for (int i = 0; i < NTW; ++i) acc[m][i] = (f32x4){0.f, 0.f, 0.f, 0.f};
    const int g8 = (lane >> 4) << 3;
    const int l8 = lane << 3;

    for (int ks = 0; ks < KS; ++ks) {
        __syncthreads();
        for (int idx = tid; idx < 2048; idx += 256) {
            const int row = idx >> 5, kk = idx & 31;
            const int k = ks * 32 + kk;
            const float v = (k < K) ? A[(size_t)(bm + row) * lda + k] : 0.f;
            unsigned short h, l; split2(v, h, l);
            Ahs[row * 40 + kk] = h; Als[row * 40 + kk] = l;
        }
        __syncthreads();
        bf16x8 ah[4], al[4];
#pragma unroll
        for (int m = 0; m < 4; ++m) {
            const int off = (m * 16 + (lane & 15)) * 40 + g8;
            ah[m] = *(const bf16x8*)(Ahs + off);
            al[m] = *(const bf16x8*)(Als + off);
        }
#pragma unroll
        for (int i = 0; i < NTW; ++i) {
            const int nt = ntb + w * NTW + i;
            const int bo = ((nt * KS + ks) << 9) + l8;
            const bf16x8 bh = *(const bf16x8*)(Bh + bo);
            const bf16x8 bl = *(const bf16x8*)(Bl + bo);
#pragma unroll
            for (int m = 0; m < 4; ++m) {
                acc[m][i] = __builtin_amdgcn_mfma_f32_16x16x32_bf16(ah[m], bh, acc[m][i], 0, 0, 0);
                acc[m][i] = __builtin_amdgcn_mfma_f32_16x16x32_bf16(al[m], bh, acc[m][i], 0, 0, 0);
                acc[m][i] = __builtin_amdgcn_mfma_f32_16x16x32_bf16(ah[m], bl, acc[m][i], 0, 0, 0);
            }
        }
    }
#pragma unroll
    for (int i = 0; i < NTW; ++i) {
        const int col = (ntb + w * NTW + i) * 16 + (lane & 15);
        if (col < Nout) {
            const float bj = bias[col];
#pragma unroll
            for (int m = 0; m < 4; ++m)
#pragma unroll
                for (int r = 0; r < 4; ++r) {
                    const int row = bm + m * 16 + ((lane >> 4) << 2) + r;
                    float v = acc[m][i][r] + bj;
                    if (RELU) v = fmaxf(v, 0.f);
                    C[(size_t)row * ldc + coff + col] = v;
                }
        }
    }
}

// ---------------------------------------------------------------------------
// Cell stage 1 with fused L2-normalize: C1 = relu(norm(cell) @ Wr1 + br1).
// ---------------------------------------------------------------------------
__global__ __launch_bounds__(256) void cell_s1(
    const float* __restrict__ cell,                       // [8192][954]
    const unsigned short* __restrict__ Bh, const unsigned short* __restrict__ Bl,
    const float* __restrict__ bias, float* __restrict__ C1)
{
    __shared__ unsigned short Ahs[64 * 40], Als[64 * 40];
    __shared__ float rn[64];
    const int tid = threadIdx.x, lane = tid & 63, w = tid >> 6;
    const int bm = blockIdx.x * 64;
    const int ntb = blockIdx.y * 16;
    const int g8 = (lane >> 4) << 3;
    const int l8 = lane << 3;

    if (tid < 64) rn[tid] = 0.f;
    __syncthreads();
    {
        const int row = tid & 63, part = tid >> 6;
        float ss = 0.f;
        for (int c = part; c < 954; c += 4) {
            const float v = cell[(size_t)(bm + row) * 954 + c];
            ss = fmaf(v, v, ss);
        }
        atomicAdd(&rn[row], ss);
    }
    __syncthreads();
    if (tid < 64) rn[tid] = 1.0f / fmaxf(sqrtf(rn[tid]), 1e-12f);

    f32x4 acc[4][4];
#pragma unroll
    for (int m = 0; m < 4; ++m)
#pragma unroll
        for (int i = 0; i < 4; ++i) acc[m][i] = (f32x4){0.f, 0.f, 0.f, 0.f};

    for (int ks = 0; ks < 30; ++ks) {
        __syncthreads();
        for (int idx = tid; idx < 2048; idx += 256) {
            const int row = idx >> 5, kk = idx & 31;
            const int k = ks * 32 + kk;
            const float v = (k < 954) ? cell[(size_t)(bm + row) * 954 + k] * rn[row] : 0.f;
            unsigned short h, l; split2(v, h, l);
            Ahs[row * 40 + kk] = h; Als[row * 40 + kk] = l;
        }
        __syncthreads();
        bf16x8 ah[4], al[4];
#pragma unroll
        for (int m = 0; m < 4; ++m) {
            const int off = (m * 16 + (lane & 15)) * 40 + g8;
            ah[m] = *(const bf16x8*)(Ahs + off);
            al[m] = *(const bf16x8*)(Als + off);
        }
#pragma unroll
        for (int i = 0; i < 4; ++i) {
            const int nt = ntb + w * 4 + i;
            const int bo = ((nt * 30 + ks) << 9) + l8;
            const bf16x8 bh = *(const bf16x8*)(Bh + bo);
            const bf16x8 bl = *(const bf16x8*)(Bl + bo);
#pragma unroll
            for (int m = 0; m < 4; ++m) {
                acc[m][i] = __builtin_amdgcn_mfma_f32_16x16x32_bf16(ah[m], bh, acc[m][i], 0, 0, 0);
                acc[m][i] = __builtin_amdgcn_mfma_f32_16x16x32_bf16(al[m], bh, acc[m][i], 0, 0, 0);
                acc[m][i] = __builtin_amdgcn_mfma_f32_16x16x32_bf16(ah[m], bl, acc[m][i], 0, 0, 0);
            }
        }
    }
#pragma unroll
    for (int i = 0; i < 4; ++i) {
        const int col = (ntb + w * 4 + i) * 16 + (lane & 15);
        const float bj = bias[col];
#pragma unroll
        for (int m = 0; m < 4; ++m)
#pragma unroll
            for (int r = 0; r < 4; ++r) {
                const int row = bm + m * 16 + ((lane >> 4) << 2) + r;
                C1[(size_t)row * 512 + col] = fmaxf(acc[m][i][r] + bj, 0.f);
            }
    }
}

// ---------------------------------------------------------------------------
// Fused drug heads: XC[:,0:128 / 128:256] = (relu(G@Wg1+bg1)) @ Wg2 + bg2.
// ---------------------------------------------------------------------------
__global__ __launch_bounds__(256) void drughead(
    const float* __restrict__ G,                           // [16384][312]
    const unsigned short* __restrict__ B1h, const unsigned short* __restrict__ B1l,
    const unsigned short* __restrict__ B2h, const unsigned short* __restrict__ B2l,
    const float* __restrict__ bg1, const float* __restrict__ bg2,
    float* __restrict__ XC)
{
    __shared__ unsigned short Ahs[64 * 40], Als[64 * 40];
    __shared__ unsigned short Th[64 * 168], Tl[64 * 168];
    const int tid = threadIdx.x, lane = tid & 63, w = tid >> 6;
    const int bm = blockIdx.x * 64;
    const int l15 = lane & 15, g8 = (lane >> 4) << 3, g4 = (lane >> 4) << 2;
    const int l8 = lane << 3;

    // ---- stage 1: T = relu(G @ Wg1 + bg1), K=312 (KS=10), N=156 (10 tiles)
    f32x4 acc[4][3];
#pragma unroll
    for (int m = 0; m < 4; ++m)
#pragma unroll
        for (int i = 0; i < 3; ++i) acc[m][i] = (f32x4){0.f, 0.f, 0.f, 0.f};
    for (int ks = 0; ks < 10; ++ks) {
        __syncthreads();
        for (int idx = tid; idx < 2048; idx += 256) {
            const int row = idx >> 5, kk = idx & 31;
            const int k = ks * 32 + kk;
            const float v = (k < 312) ? G[(size_t)(bm + row) * 312 + k] : 0.f;
            unsigned short h, l; split2(v, h, l);
            Ahs[row * 40 + kk] = h; Als[row * 40 + kk] = l;
        }
        __syncthreads();
        bf16x8 ah[4], al[4];
#pragma unroll
        for (int m = 0; m < 4; ++m) {
            const int off = (m * 16 + l15) * 40 + g8;
            ah[m] = *(const bf16x8*)(Ahs + off);
            al[m] = *(const bf16x8*)(Als + off);
        }
#pragma unroll
        for (int i = 0; i < 3; ++i) {
            const int nt = w + 4 * i;
            if (nt < 10) {
                const int bo = ((nt * 10 + ks) << 9) + l8;
                const bf16x8 bh = *(const bf16x8*)(B1h + bo);
                const bf16x8 bl = *(const bf16x8*)(B1l + bo);
#pragma unroll
                for (int m = 0; m < 4; ++m) {
                    acc[m][i] = __builtin_amdgcn_mfma_f32_16x16x32_bf16(ah[m], bh, acc[m][i], 0, 0, 0);
                    acc[m][i] = __builtin_amdgcn_mfma_f32_16x16x32_bf16(al[m], bh, acc[m][i], 0, 0, 0);
                    acc[m][i] = __builtin_amdgcn_mfma_f32_16x16x32_bf16(ah[m], bl, acc[m][i], 0, 0, 0);
                }
            }
        }
    }
    // epi1: relu+bias, split -> T (cols 156..159 zeroed for NaN safety)
#pragma unroll
    for (int i = 0; i < 3; ++i) {
        const int nt = w + 4 * i;
        if (nt < 10) {
            const int col = nt * 16 + l15;
            const float bj = (col < 156) ? bg1[col] : 0.f;
#pragma unroll
            for (int m = 0; m < 4; ++m)
#pragma unroll
                for (int r = 0; r < 4; ++r) {
                    const int row = m * 16 + g4 + r;
                    float v = (col < 156) ? fmaxf(acc[m][i][r] + bj, 0.f) : 0.f;
                    unsigned short h, l; split2(v, h, l);
                    Th[row * 168 + col] = h;
                    Tl[row * 168 + col] = l;
                }
        }
    }
    __syncthreads();

    // ---- stage 2: XC cols = T @ Wg2 + bg2, K=156 (KS=5), N=128 (8 tiles)
    f32x4 acc2[4][2];
#pragma unroll
    for (int m = 0; m < 4; ++m)
#pragma unroll
        for (int i = 0; i < 2; ++i) acc2[m][i] = (f32x4){0.f, 0.f, 0.f, 0.f};
#pragma unroll
    for (int ks = 0; ks < 5; ++ks) {
        bf16x8 ah[4], al[4];
#pragma unroll
        for (int m = 0; m < 4; ++m) {
            const int off = (m * 16 + l15) * 168 + ks * 32 + g8;
            ah[m] = *(const bf16x8*)(Th + off);
            al[m] = *(const bf16x8*)(Tl + off);
        }
#pragma unroll
        for (int i = 0; i < 2; ++i) {
            const int nt = w + 4 * i;
            const int bo = ((nt * 5 + ks) << 9) + l8;
            const bf16x8 bh = *(const bf16x8*)(B2h + bo);
            const bf16x8 bl = *(const bf16x8*)(B2l + bo);
#pragma unroll
            for (int m = 0; m < 4; ++m) {
                acc2[m][i] = __builtin_amdgcn_mfma_f32_16x16x32_bf16(ah[m], bh, acc2[m][i], 0, 0, 0);
                acc2[m][i] = __builtin_amdgcn_mfma_f32_16x16x32_bf16(al[m], bh, acc2[m][i], 0, 0, 0);
                acc2[m][i] = __builtin_amdgcn_mfma_f32_16x16x32_bf16(ah[m], bl, acc2[m][i], 0, 0, 0);
            }
        }
    }
#pragma unroll
    for (int i = 0; i < 2; ++i) {
        const int col = (w + 4 * i) * 16 + l15;
        const float bj = bg2[col];
#pragma unroll
        for (int m = 0; m < 4; ++m)
#pragma unroll
            for (int r = 0; r < 4; ++r) {
                const int row = bm + m * 16 + g4 + r;
                const int crow = row & (BGRAPH - 1);
                const int cadd = (row >> 13) * 128;
                XC[(size_t)crow * 384 + cadd + col] = acc2[m][i][r] + bj;
            }
    }
}

// ---------------------------------------------------------------------------
// Fused head: out = (relu(relu(XC@Wf1+bf1)@Wf2+bf2)) @ Wo + bo.
// ---------------------------------------------------------------------------
__global__ __launch_bounds__(256) void head_fused(
    const float* __restrict__ XC,                          // [8192][384]
    const unsigned short* __restrict__ B1h, const unsigned short* __restrict__ B1l,
    const unsigned short* __restrict__ B2h, const unsigned short* __restrict__ B2l,
    const unsigned short* __restrict__ B3h, const unsigned short* __restrict__ B3l,
    const float* __restrict__ bf1, const float* __restrict__ bf2, const float* __restrict__ bo,
    float* __restrict__ out)
{
    __shared__ unsigned short Ahs[32 * 40], Als[32 * 40];
    __shared__ unsigned short T1h[32 * 280], T1l[32 * 280];
    unsigned short* T2h = T1h;                             // aliased, stride 136
    unsigned short* T2l = T1l;
    const int tid = threadIdx.x, lane = tid & 63, w = tid >> 6;
    const int bm = blockIdx.x * 32;
    const int l15 = lane & 15, g8 = (lane >> 4) << 3, g4 = (lane >> 4) << 2;
    const int l8 = lane << 3;

    // ---- stage 1: T1 = relu(XC @ Wf1 + bf1), K=384 (KS=12), N=256 (16 tiles)
    f32x4 acc[2][4];
#pragma unroll
    for (int m = 0; m < 2; ++m)
#pragma unroll
        for (int i = 0; i < 4; ++i) acc[m][i] = (f32x4){0.f, 0.f, 0.f, 0.f};
    for (int ks = 0; ks < 12; ++ks) {
        __syncthreads();
        for (int idx = tid; idx < 1024; idx += 256) {
            const int row = idx >> 5, kk = idx & 31;
            const int k = ks * 32 + kk;
            const float v = XC[(size_t)(bm + row) * 384 + k];   // K=384 exact
            unsigned short h, l; split2(v, h, l);
            Ahs[row * 40 + kk] = h; Als[row * 40 + kk] = l;
        }
        __syncthreads();
        bf16x8 ah[2], al[2];
#pragma unroll
        for (int m = 0; m < 2; ++m) {
            const int off = (m * 16 + l15) * 40 + g8;
            ah[m] = *(const bf16x8*)(Ahs + off);
            al[m] = *(const bf16x8*)(Als + off);
        }
#pragma unroll
        for (int i = 0; i < 4; ++i) {
            const int nt = w + 4 * i;
            const int bo_ = ((nt * 12 + ks) << 9) + l8;
            const bf16x8 bh = *(const bf16x8*)(B1h + bo_);
            const bf16x8 bl = *(const bf16x8*)(B1l + bo_);
#pragma unroll
            for (int m = 0; m < 2; ++m) {
                acc[m][i] = __builtin_amdgcn_mfma_f32_16x16x32_bf16(ah[m], bh, acc[m][i], 0, 0, 0);
                acc[m][i] = __builtin_amdgcn_mfma_f32_16x16x32_bf16(al[m], bh, acc[m][i], 0, 0, 0);
                acc[m][i] = __builtin_amdgcn_mfma_f32_16x16x32_bf16(ah[m], bl, acc[m][i], 0, 0, 0);
            }
        }
    }
#pragma unroll
    for (int i = 0; i < 4; ++i) {
        const int col = (w + 4 * i) * 16 + l15;
        const float bj = bf1[col];
#pragma unroll
        for (int m = 0; m < 2; ++m)
#pragma unroll
            for (int r = 0; r < 4; ++r) {
                const int row = m * 16 + g4 + r;
                const float v = fmaxf(acc[m][i][r] + bj, 0.f);
                unsigned short h, l; split2(v, h, l);
                T1h[row * 280 + col] = h;
                T1l[row * 280 + col] = l;
            }
    }
    __syncthreads();

    // ---- stage 2: T2 = relu(T1 @ Wf2 + bf2), K=256 (KS=8), N=128 (8 tiles)
    f32x4 acc2[2][2];
#pragma unroll
    for (int m = 0; m < 2; ++m)
#pragma unroll
        for (int i = 0; i < 2; ++i) acc2[m][i] = (f32x4){0.f, 0.f, 0.f, 0.f};
#pragma unroll
    for (int ks = 0; ks < 8; ++ks) {
        bf16x8 ah[2], al[2];
#pragma unroll
        for (int m = 0; m < 2; ++m) {
            const int off = (m * 16 + l15) * 280 + ks * 32 + g8;
            ah[m] = *(const bf16x8*)(T1h + off);
            al[m] = *(const bf16x8*)(T1l + off);
        }
#pragma unroll
        for (int i = 0; i < 2; ++i) {
            const int nt = w + 4 * i;
            const int bo_ = ((nt * 8 + ks) << 9) + l8;
            const bf16x8 bh = *(const bf16x8*)(B2h + bo_);
            const bf16x8 bl = *(const bf16x8*)(B2l + bo_);
#pragma unroll
            for (int m = 0; m < 2; ++m) {
                acc2[m][i] = __builtin_amdgcn_mfma_f32_16x16x32_bf16(ah[m], bh, acc2[m][i], 0, 0, 0);
                acc2[m][i] = __builtin_amdgcn_mfma_f32_16x16x32_bf16(al[m], bh, acc2[m][i], 0, 0, 0);
                acc2[m][i] = __builtin_amdgcn_mfma_f32_16x16x32_bf16(ah[m], bl, acc2[m][i], 0, 0, 0);
            }
        }
    }
    __syncthreads();                       // all T1 reads done (T2 aliases T1)
#pragma unroll
    for (int i = 0; i < 2; ++i) {
        const int col = (w + 4 * i) * 16 + l15;
        const float bj = bf2[col];
#pragma unroll
        for (int m = 0; m < 2; ++m)
#pragma unroll
            for (int r = 0; r < 4; ++r) {
                const int row = m * 16 + g4 + r;
                const float v = fmaxf(acc2[m][i][r] + bj, 0.f);
                unsigned short h, l; split2(v, h, l);
                T2h[row * 136 + col] = h;
                T2l[row * 136 + col] = l;
            }
    }
    __syncthreads();

    // ---- stage 3: out = T2 @ Wo + bo, K=128 (KS=4), N=2 (tile 0, wave 0)
    if (w == 0) {
        f32x4 acc3[2];
        acc3[0] = (f32x4){0.f, 0.f, 0.f, 0.f};
        acc3[1] = (f32x4){0.f, 0.f, 0.f, 0.f};
#pragma unroll
        for (int ks = 0; ks < 4; ++ks) {
            bf16x8 ah[2], al[2];
#pragma unroll
            for (int m = 0; m < 2; ++m) {
                const int off = (m * 16 + l15) * 136 + ks * 32 + g8;
                ah[m] = *(const bf16x8*)(T2h + off);
                al[m] = *(const bf16x8*)(T2l + off);
            }
            const int bo_ = (ks << 9) + l8;
            const bf16x8 bh = *(const bf16x8*)(B3h + bo_);
            const bf16x8 bl = *(const bf16x8*)(B3l + bo_);
#pragma unroll
            for (int m = 0; m < 2; ++m) {
                acc3[m] = __builtin_amdgcn_mfma_f32_16x16x32_bf16(ah[m], bh, acc3[m], 0, 0, 0);
                acc3[m] = __builtin_amdgcn_mfma_f32_16x16x32_bf16(al[m], bh, acc3[m], 0, 0, 0);
                acc3[m] = __builtin_amdgcn_mfma_f32_16x16x32_bf16(ah[m], bl, acc3[m], 0, 0, 0);
            }
        }
        if (l15 < 2) {
            const float bj = bo[l15];
#pragma unroll
            for (int m = 0; m < 2; ++m)
#pragma unroll
                for (int r = 0; r < 4; ++r)
                    out[(size_t)(bm + m * 16 + g4 + r) * 2 + l15] = acc3[m][r] + bj;
        }
    }
}

// ---------------------------------------------------------------------------

extern "C" void kernel_launch(void* const* d_in, const int* in_sizes, int n_in,
                              void* d_out, int out_size, void* d_ws, size_t ws_size,
                              hipStream_t stream)
{
    (void)in_sizes; (void)n_in; (void)out_size; (void)ws_size;
    const float* x1   = (const float*)d_in[0];
    const int*   ei1  = (const int*)d_in[1];
    const float* x2   = (const float*)d_in[3];
    const int*   ei2  = (const int*)d_in[4];
    const float* cell = (const float*)d_in[6];
    const float* Wc1 = (const float*)d_in[7],  *bc1 = (const float*)d_in[8];
    const float* Wc2 = (const float*)d_in[9],  *bc2 = (const float*)d_in[10];
    const float* Wc3 = (const float*)d_in[11], *bc3 = (const float*)d_in[12];
    const float* Wg1 = (const float*)d_in[13], *bg1 = (const float*)d_in[14];
    const float* Wg2 = (const float*)d_in[15], *bg2 = (const float*)d_in[16];
    const float* Wr1 = (const float*)d_in[17], *br1 = (const float*)d_in[18];
    const float* Wr2 = (const float*)d_in[19], *br2 = (const float*)d_in[20];
    const float* Wr3 = (const float*)d_in[21], *br3 = (const float*)d_in[22];
    const float* Wf1 = (const float*)d_in[23], *bf1 = (const float*)d_in[24];
    const float* Wf2 = (const float*)d_in[25], *bf2 = (const float*)d_in[26];
    const float* Wo  = (const float*)d_in[27], *bo  = (const float*)d_in[28];
    float* out = (float*)d_out;
    float* ws  = (float*)d_ws;

    size_t o = 0;
    auto allocF = [&](size_t n) { float* p = ws + o; o += n; return p; };
    auto allocU = [&](size_t n) { unsigned short* p = (unsigned short*)(ws + o); o += n / 2; return p; };

    float* G1  = allocF((size_t)2 * BGRAPH * 312);   // both branches stacked
    float* C1  = allocF((size_t)BGRAPH * 512);
    float* C2  = allocF((size_t)BGRAPH * 256);
    float* XC  = allocF((size_t)BGRAPH * 384);

    // swizzled split weights (ushort counts = NT*KS*512)
    const int sWc1 = 8  * 3  * 512, sWc2 = 12 * 3  * 512, sWc3 = 20 * 5  * 512;
    const int sWg1 = 10 * 10 * 512, sWg2 = 8  * 5  * 512;
    const int sWr1 = 32 * 30 * 512, sWr2 = 16 * 16 * 512, sWr3 = 8 * 8 * 512;
    const int sWf1 = 16 * 12 * 512, sWf2 = 8  * 8  * 512, sWoo = 1 * 4 * 512;
    unsigned short *Wc1h = allocU(sWc1), *Wc1l = allocU(sWc1);
    unsigned short *Wc2h = allocU(sWc2), *Wc2l = allocU(sWc2);
    unsigned short *Wc3h = allocU(sWc3), *Wc3l = allocU(sWc3);
    unsigned short *Wg1h = allocU(sWg1), *Wg1l = allocU(sWg1);
    unsigned short *Wg2h = allocU(sWg2), *Wg2l = allocU(sWg2);
    unsigned short *Wr1h = allocU(sWr1), *Wr1l = allocU(sWr1);
    unsigned short *Wr2h = allocU(sWr2), *Wr2l = allocU(sWr2);
    unsigned short *Wr3h = allocU(sWr3), *Wr3l = allocU(sWr3);
    unsigned short *Wf1h = allocU(sWf1), *Wf1l = allocU(sWf1);
    unsigned short *Wf2h = allocU(sWf2), *Wf2l = allocU(sWf2);
    unsigned short *Wooh = allocU(sWoo), *Wool = allocU(sWoo);

    // one fused weight-prep launch
    WTab tab;
    int base = 0, ti = 0;
    auto addw = [&](const float* W, int K, int N, int KS, int NT,
                    unsigned short* Bh, unsigned short* Bl) {
        tab.d[ti] = WDesc{W, Bh, Bl, K, N, KS, NT, base};
        base += NT * KS * 2;              // blocks = NT*KS*512/256
        ++ti;
    };
    addw(Wc1, 78, 78, 3, 8, Wc1h, Wc1l);
    addw(Wc2, 78, 156, 3, 12, Wc2h, Wc2l);
    addw(Wc3, 156, 312, 5, 20, Wc3h, Wc3l);
    addw(Wg1, 312, 156, 10, 10, Wg1h, Wg1l);
    addw(Wg2, 156, 128, 5, 8, Wg2h, Wg2l);
    addw(Wr1, 954, 512, 30, 32, Wr1h, Wr1l);
    addw(Wr2, 512, 256, 16, 16, Wr2h, Wr2l);
    addw(Wr3, 256, 128, 8, 8, Wr3h, Wr3l);
    addw(Wf1, 384, 256, 12, 16, Wf1h, Wf1l);
    addw(Wf2, 256, 128, 8, 8, Wf2h, Wf2l);
    addw(Wo,  128, 2,   4, 1, Wooh, Wool);
    wprep_all<<<base, 256, 0, stream>>>(tab);

    // both drug branches, 2 graphs per block with phase-offset dual-pipe slots
    gcn_graph2<<<BGRAPH, GT, 0, stream>>>(x1, ei1, x2, ei2,
        Wc1h, Wc1l, Wc2h, Wc2l, Wc3h, Wc3l, bc1, bc2, bc3, G1);

    // fused drug heads (M = 16384): G -> XC[:,0:128] / [:,128:256]
    drughead<<<256, 256, 0, stream>>>(G1, Wg1h, Wg1l, Wg2h, Wg2l, bg1, bg2, XC);

    // cell MLP -> XC[:,256:384] (stage 1 fuses the L2 normalize)
    cell_s1<<<dim3(128, 2), 256, 0, stream>>>(cell, Wr1h, Wr1l, br1, C1);
    gemm_dense<2, true ><<<dim3(128, 2), 256, 0, stream>>>(C1, 512, 512, 16, Wr2h, Wr2l, br2, 256, C2, 256, 0);
    gemm_dense<1, false><<<dim3(128, 2), 256, 0, stream>>>(C2, 256, 256, 8, Wr3h, Wr3l, br3, 128, XC, 384, 256);

    // fused head: XC -> out
    head_fused<<<256, 256, 0, stream>>>(XC, Wf1h, Wf1l, Wf2h, Wf2l, Wooh, Wool,
                                        bf1, bf2, bo, out);
}

// Round 11
// 938.909 us; speedup vs baseline: 1.2460x; 1.2460x over previous
//
#include <hip/hip_runtime.h>
#include <math.h>

#define EE 819200          // edges total
#define BGRAPH 8192        // graphs
constexpr int GT = 512;    // threads, graph kernel (8 waves)

typedef __attribute__((ext_vector_type(8))) short bf16x8;   // 4 VGPRs = 8 bf16
typedef __attribute__((ext_vector_type(4))) float f32x4;

// ---- fp32 -> bf16 split (RNE), a ~= hi + lo, |a-(hi+lo)| <= 2^-18 |a| ----
__device__ inline unsigned short f2bf(float x) {
    unsigned u = __float_as_uint(x);
    u += 0x7fffu + ((u >> 16) & 1u);
    return (unsigned short)(u >> 16);
}
__device__ inline float bf2f(unsigned short h) {
    return __uint_as_float(((unsigned)h) << 16);
}
__device__ inline void split2(float v, unsigned short& hi, unsigned short& lo) {
    hi = f2bf(v);
    lo = f2bf(v - bf2f(hi));
}
// packed RNE split of a value-pair: h = {bf16(b)|bf16(a)}, l = residuals
__device__ inline unsigned cvtpk_bf16(float a, float b) {
    unsigned r;
    asm("v_cvt_pk_bf16_f32 %0, %1, %2" : "=v"(r) : "v"(a), "v"(b));
    return r;
}
__device__ inline void split_pair(float a, float b, unsigned& h, unsigned& l) {
    h = cvtpk_bf16(a, b);
    const float ra = a - __uint_as_float(h << 16);
    const float rb = b - __uint_as_float(h & 0xffff0000u);
    l = cvtpk_bf16(ra, rb);
}

// ---------------------------------------------------------------------------
// Fused weight prep (one launch): W[K][N] fp32 -> fragment-ordered hi/lo bf16,
// zero-padded to (KS*32) x (NT*16).
// ---------------------------------------------------------------------------
struct WDesc { const float* W; unsigned short* Bh; unsigned short* Bl;
               int K, N, KS, NT, base; };
struct WTab { WDesc d[11]; };

__global__ __launch_bounds__(256) void wprep_all(WTab tab)
{
    const int bid = blockIdx.x;
    int t = 0;
#pragma unroll
    for (int i = 1; i < 11; ++i) if (bid >= tab.d[i].base) t = i;
    const WDesc D = tab.d[t];
    const int idx = (bid - D.base) * 256 + (int)threadIdx.x;
    if (idx >= D.NT * D.KS * 512) return;
    const int r    = idx & 7;
    const int lane = (idx >> 3) & 63;
    const int rest = idx >> 9;
    const int ks   = rest % D.KS;
    const int nt   = rest / D.KS;
    const int k = ks * 32 + ((lane >> 4) << 3) + r;
    const int n = nt * 16 + (lane & 15);
    const float v = (k < D.K && n < D.N) ? D.W[(size_t)k * D.N + n] : 0.f;
    unsigned short h, l; split2(v, h, l);
    D.Bh[idx] = h; D.Bl[idx] = l;
}

// ---------------------------------------------------------------------------
// Per-graph fused 3-layer GCN + max pool, bf16x3 MFMA (R9 structure).
// act fp32 [50][164] (odd float4 stride 41 -> gather banks spread by node+chunk,
// fixes the 6-way conflict of stride 160). Frags [50][168] hi/lo.
// ---------------------------------------------------------------------------

template<int KS, int NI, int FOUT>   // K-steps; n-tiles/wave; real out cols
__device__ inline void layer_run(const unsigned short* __restrict__ Bh,
                                 const unsigned short* __restrict__ Bl,
                                 const unsigned short* Ah, const unsigned short* Al,
                                 f32x4 (&acc)[2][5], int mg, int ng, int lane)
{
#pragma unroll
    for (int m = 0; m < 2; ++m)
#pragma unroll
        for (int i = 0; i < NI; ++i) acc[m][i] = (f32x4){0.f, 0.f, 0.f, 0.f};
    const int g8 = (lane >> 4) << 3;
    const int l8 = lane << 3;
#pragma unroll
    for (int ks = 0; ks < KS; ++ks) {
        bf16x8 ah[2], al[2];
#pragma unroll
        for (int m = 0; m < 2; ++m) {
            const int off = (mg * 32 + m * 16 + (lane & 15)) * 168 + ks * 32 + g8;
            ah[m] = *(const bf16x8*)(Ah + off);
            al[m] = *(const bf16x8*)(Al + off);
        }
#pragma unroll
        for (int i = 0; i < NI; ++i) {
            const int nt = ng + (i << 2);
            if (nt * 16 < FOUT) {              // skip all-zero W tiles (uniform)
                const int bo = ((nt * KS + ks) << 9) + l8;
                const bf16x8 bh = *(const bf16x8*)(Bh + bo);
                const bf16x8 bl = *(const bf16x8*)(Bl + bo);
#pragma unroll
                for (int m = 0; m < 2; ++m) {
                    acc[m][i] = __builtin_amdgcn_mfma_f32_16x16x32_bf16(ah[m], bh, acc[m][i], 0, 0, 0);
                    acc[m][i] = __builtin_amdgcn_mfma_f32_16x16x32_bf16(al[m], bh, acc[m][i], 0, 0, 0);
                    acc[m][i] = __builtin_amdgcn_mfma_f32_16x16x32_bf16(ah[m], bl, acc[m][i], 0, 0, 0);
                }
            }
        }
    }
}

// D layout: col = lane&15 (+16*nt), row = (lane>>4)*4 + reg (+16*mt)
template<int NI, int NCOL>
__device__ inline void epi_store(const f32x4 (&acc)[2][5], const float* __restrict__ bias,
                                 float* act, int mg, int ng, int lane)
{
#pragma unroll
    for (int i = 0; i < NI; ++i) {
        const int col = (ng + (i << 2)) * 16 + (lane & 15);
        if (col < NCOL) {
            const float bj = bias[col];
#pragma unroll
            for (int m = 0; m < 2; ++m)
#pragma unroll
                for (int r = 0; r < 4; ++r) {
                    const int row = mg * 32 + m * 16 + ((lane >> 4) << 2) + r;
                    if (row < 50)
                        act[row * 164 + col] = fmaxf(acc[m][i][r] + bj, 0.f);
                }
        }
    }
}

__device__ inline void pool_store(const f32x4 (&acc)[2][5], const float* __restrict__ bias,
                                  unsigned* gmax, int mg, int ng, int lane)
{
#pragma unroll
    for (int i = 0; i < 5; ++i) {
        const int col = (ng + (i << 2)) * 16 + (lane & 15);
        const float bj = (col < 312) ? bias[col] : 0.f;
        float m = 0.f;                      // relu floor == pool identity
#pragma unroll
        for (int mm = 0; mm < 2; ++mm)
#pragma unroll
            for (int r = 0; r < 4; ++r) {
                const int row = mg * 32 + mm * 16 + ((lane >> 4) << 2) + r;
                if (row < 50) m = fmaxf(m, acc[mm][i][r] + bj);
            }
        m = fmaxf(m, __shfl_xor(m, 16, 64));
        m = fmaxf(m, __shfl_xor(m, 32, 64));
        if (lane < 16 && col < 312)
            atomicMax(&gmax[col], __float_as_uint(m));
    }
}

// agg (Â·H) fused with bf16-split, 8 features/item (two float4 chains),
// edge-pair unrolling, cvt_pk RNE splits, b128 stores. act4 stride 41 (odd).
template<int NCOL>
__device__ inline void agg_split8(const float4* __restrict__ act4,
                                  unsigned short* Ah, unsigned short* Al,
                                  const int* insrc, const float* insn,
                                  const int* inoff, const float* selfw, int tid)
{
    constexpr int CH = (NCOL + 7) / 8;     // 8-float chunks per row (pads zero)
    for (int idx = tid; idx < 50 * CH; idx += GT) {
        const int n = idx / CH;            // constexpr divisor -> magic-mul
        const int c2 = (idx - n * CH) * 2; // float4 index within row
        const float sw = selfw[n];
        const float4 v0 = act4[n * 41 + c2];
        const float4 v1 = act4[n * 41 + c2 + 1];
        float4 a0, a1;
        a0.x = sw * v0.x; a0.y = sw * v0.y; a0.z = sw * v0.z; a0.w = sw * v0.w;
        a1.x = sw * v1.x; a1.y = sw * v1.y; a1.z = sw * v1.z; a1.w = sw * v1.w;
        int j = inoff[n];
        const int j1 = inoff[n + 1];
        for (; j + 1 < j1; j += 2) {
            const int s0 = insrc[j] * 41 + c2;
            const int s1 = insrc[j + 1] * 41 + c2;
            const float w0 = insn[j], w1 = insn[j + 1];
            const float4 e00 = act4[s0], e01 = act4[s0 + 1];
            const float4 e10 = act4[s1], e11 = act4[s1 + 1];
            a0.x = fmaf(w1, e10.x, fmaf(w0, e00.x, a0.x));
            a0.y = fmaf(w1, e10.y, fmaf(w0, e00.y, a0.y));
            a0.z = fmaf(w1, e10.z, fmaf(w0, e00.z, a0.z));
            a0.w = fmaf(w1, e10.w, fmaf(w0, e00.w, a0.w));
            a1.x = fmaf(w1, e11.x, fmaf(w0, e01.x, a1.x));
            a1.y = fmaf(w1, e11.y, fmaf(w0, e01.y, a1.y));
            a1.z = fmaf(w1, e11.z, fmaf(w0, e01.z, a1.z));
            a1.w = fmaf(w1, e11.w, fmaf(w0, e01.w, a1.w));
        }
        if (j < j1) {
            const int s0 = insrc[j] * 41 + c2;
            const float w0 = insn[j];
            const float4 e00 = act4[s0], e01 = act4[s0 + 1];
            a0.x = fmaf(w0, e00.x, a0.x);
            a0.y = fmaf(w0, e00.y, a0.y);
            a0.z = fmaf(w0, e00.z, a0.z);
            a0.w = fmaf(w0, e00.w, a0.w);
            a1.x = fmaf(w0, e01.x, a1.x);
            a1.y = fmaf(w0, e01.y, a1.y);
            a1.z = fmaf(w0, e01.z, a1.z);
            a1.w = fmaf(w0, e01.w, a1.w);
        }
        unsigned h01, h23, h45, h67, l01, l23, l45, l67;
        split_pair(a0.x, a0.y, h01, l01);
        split_pair(a0.z, a0.w, h23, l23);
        split_pair(a1.x, a1.y, h45, l45);
        split_pair(a1.z, a1.w, h67, l67);
        const int off = n * 168 + (c2 << 2);           // 16B-aligned
        *(uint4*)(Ah + off) = make_uint4(h01, h23, h45, h67);
        *(uint4*)(Al + off) = make_uint4(l01, l23, l45, l67);
    }
}

__global__ __launch_bounds__(GT, 4) void gcn_graph(
    const float* __restrict__ x1, const int* __restrict__ ei1,
    const float* __restrict__ x2, const int* __restrict__ ei2,
    const unsigned short* __restrict__ W1h, const unsigned short* __restrict__ W1l,
    const unsigned short* __restrict__ W2h, const unsigned short* __restrict__ W2l,
    const unsigned short* __restrict__ W3h, const unsigned short* __restrict__ W3l,
    const float* __restrict__ bc1, const float* __restrict__ bc2, const float* __restrict__ bc3,
    float* __restrict__ G)              // [2*B,312]
{
    __shared__ __align__(16) unsigned short Ah[50 * 168], Al[50 * 168];
    __shared__ float4 act4s[50 * 41];                       // fp32 act [50][164]
    __shared__ int   es[100], ed[100], insrc[100];
    __shared__ float insn[100];
    __shared__ int   inoff[51], cnt[50], cnt2[50];
    __shared__ float dinvs[50], selfw[50];
    __shared__ unsigned gmax[312];

    const int br = blockIdx.x >> 13;
    const int b  = blockIdx.x & (BGRAPH - 1);
    const float* X    = br ? x2 : x1;
    const int*   srcA = br ? ei2 : ei1;
    const int*   dstA = srcA + EE;
    const int nb = b * 50, eb = b * 100, tid = threadIdx.x;
    const int lane = tid & 63;
    const int w = tid >> 6;
    const int mg = w >> 2, ng = w & 3;
    float* act = (float*)act4s;
    const float4* act4 = act4s;

    // ---- P1: issue X loads into regs (latency hides under CSR build),
    //          zero only what must be zero, load edges
    float xreg[8];
    {
        int xc = 0;
        for (int idx = tid; idx < 3900; idx += GT)          // fully coalesced
            xreg[xc++] = X[(size_t)nb * 78 + idx];
    }
    // act zero bands: cols 78,79 (L1/L2 agg tail) + 156..159 (L3 agg tail)
    for (int i = tid; i < 300; i += GT) {
        const int n = i / 6, j = i - 6 * n;
        act[n * 164 + (j < 2 ? 78 + j : 154 + j)] = 0.f;
    }
    // frag k-band cols 80..95 rows 0..49 (NaN safety: L1/L2 write cols<80,
    // ks=2 reads k 64..95; W zero-pad nullifies VALUE but not NaN garbage)
    for (int i = tid; i < 50 * 8; i += GT) {
        const int n = i >> 3, c = ((i & 7) << 1) + 80;
        *(unsigned*)(Ah + n * 168 + c) = 0u;
        *(unsigned*)(Al + n * 168 + c) = 0u;
    }
    for (int i = tid; i < 312; i += GT) gmax[i] = 0u;
    for (int i = tid; i < 50; i += GT) { cnt[i] = 0; cnt2[i] = 0; }
    for (int e = tid; e < 100; e += GT) { es[e] = srcA[eb + e] - nb; ed[e] = dstA[eb + e] - nb; }
    __syncthreads();
    // ---- P2: degree count
    for (int e = tid; e < 100; e += GT) atomicAdd(&cnt[ed[e]], 1);
    __syncthreads();
    // ---- P3: dinv/selfw (parallel) + serial prefix (tid 0)
    for (int n = tid; n < 50; n += GT) {
        const float dv = 1.0f / sqrtf((float)cnt[n] + 1.0f);
        dinvs[n] = dv; selfw[n] = dv * dv;
    }
    if (tid == 0) { int off = 0; for (int n = 0; n < 50; ++n) { inoff[n] = off; off += cnt[n]; } inoff[50] = off; }
    __syncthreads();
    // ---- P4: counting sort (cnt2) + X reg->LDS
    for (int e = tid; e < 100; e += GT) {
        const int d = ed[e];
        const int p = inoff[d] + atomicAdd(&cnt2[d], 1);
        insrc[p] = es[e];
        insn[p]  = dinvs[es[e]] * dinvs[d];
    }
    {
        int xc = 0;
        for (int idx = tid; idx < 3900; idx += GT) {
            const int n = idx / 78, c = idx - n * 78;
            act[n * 164 + c] = xreg[xc++];
        }
    }
    __syncthreads();

    f32x4 acc[2][5];

    // layer 1: agg(X) -> 78x78
    agg_split8<78>(act4, Ah, Al, insrc, insn, inoff, selfw, tid);
    __syncthreads();
    __builtin_amdgcn_s_setprio(1);
    layer_run<3, 2, 78>(W1h, W1l, Ah, Al, acc, mg, ng, lane);
    __builtin_amdgcn_s_setprio(0);
    epi_store<2, 78>(acc, bc1, act, mg, ng, lane);
    __syncthreads();

    // layer 2: agg -> 78x156
    agg_split8<78>(act4, Ah, Al, insrc, insn, inoff, selfw, tid);
    __syncthreads();
    __builtin_amdgcn_s_setprio(1);
    layer_run<3, 3, 156>(W2h, W2l, Ah, Al, acc, mg, ng, lane);
    __builtin_amdgcn_s_setprio(0);
    epi_store<3, 156>(acc, bc2, act, mg, ng, lane);
    __syncthreads();

    // layer 3: agg -> 156x312 + fused bias/relu/maxpool
    agg_split8<156>(act4, Ah, Al, insrc, insn, inoff, selfw, tid);
    __syncthreads();
    __builtin_amdgcn_s_setprio(1);
    layer_run<5, 5, 312>(W3h, W3l, Ah, Al, acc, mg, ng, lane);
    __builtin_amdgcn_s_setprio(0);
    pool_store(acc, bc3, gmax, mg, ng, lane);
    __syncthreads();
    for (int f = tid; f < 312; f += GT)
        G[(size_t)(br * BGRAPH + b) * 312 + f] = __uint_as_float(gmax[f]);
}

// ---------------------------------------------------------------------------
// Cell stage 1 with fused L2-normalize: C1 = relu(norm(cell) @ Wr1 + br1).
// Vectorized staging: float2 loads + cvt_pk split (954 rows are 8B-aligned).
// ---------------------------------------------------------------------------
__global__ __launch_bounds__(256) void cell_s1(
    const float* __restrict__ cell,                       // [8192][954]
    const unsigned short* __restrict__ Bh, const unsigned short* __restrict__ Bl,
    const float* __restrict__ bias, float* __restrict__ C1)
{
    __shared__ unsigned short Ahs[64 * 40], Als[64 * 40];
    __shared__ float rn[64];
    const int tid = threadIdx.x, lane = tid & 63, w = tid >> 6;
    const int bm = blockIdx.x * 64;
    const int ntb = blockIdx.y * 16;
    const int g8 = (lane >> 4) << 3;
    const int l8 = lane << 3;

    if (tid < 64) rn[tid] = 0.f;
    __syncthreads();
    {
        const int row = tid & 63, part = tid >> 6;
        float ss = 0.f;
        for (int c = part; c < 954; c += 4) {
            const float v = cell[(size_t)(bm + row) * 954 + c];
            ss = fmaf(v, v, ss);
        }
        atomicAdd(&rn[row], ss);
    }
    __syncthreads();
    if (tid < 64) rn[tid] = 1.0f / fmaxf(sqrtf(rn[tid]), 1e-12f);

    f32x4 acc[4][4];
#pragma unroll
    for (int m = 0; m < 4; ++m)
#pragma unroll
        for (int i = 0; i < 4; ++i) acc[m][i] = (f32x4){0.f, 0.f, 0.f, 0.f};

    for (int ks = 0; ks < 30; ++ks) {
        __syncthreads();
        for (int idx = tid; idx < 1024; idx += 256) {
            const int row = idx >> 4, p = idx & 15;
            const int k = ks * 32 + p * 2;
            float2 v = (k < 954) ? *(const float2*)(cell + (size_t)(bm + row) * 954 + k)
                                 : make_float2(0.f, 0.f);
            const float rr = rn[row];
            unsigned h, l; split_pair(v.x * rr, v.y * rr, h, l);
            *(unsigned*)(Ahs + row * 40 + p * 2) = h;
            *(unsigned*)(Als + row * 40 + p * 2) = l;
        }
        __syncthreads();
        bf16x8 ah[4], al[4];
#pragma unroll
        for (int m = 0; m < 4; ++m) {
            const int off = (m * 16 + (lane & 15)) * 40 + g8;
            ah[m] = *(const bf16x8*)(Ahs + off);
            al[m] = *(const bf16x8*)(Als + off);
        }
#pragma unroll
        for (int i = 0; i < 4; ++i) {
            const int nt = ntb + w * 4 + i;
            const int bo = ((nt * 30 + ks) << 9) + l8;
            const bf16x8 bh = *(const bf16x8*)(Bh + bo);
            const bf16x8 bl = *(const bf16x8*)(Bl + bo);
#pragma unroll
            for (int m = 0; m < 4; ++m) {
                acc[m][i] = __builtin_amdgcn_mfma_f32_16x16x32_bf16(ah[m], bh, acc[m][i], 0, 0, 0);
                acc[m][i] = __builtin_amdgcn_mfma_f32_16x16x32_bf16(al[m], bh, acc[m][i], 0, 0, 0);
                acc[m][i] = __builtin_amdgcn_mfma_f32_16x16x32_bf16(ah[m], bl, acc[m][i], 0, 0, 0);
            }
        }
    }
#pragma unroll
    for (int i = 0; i < 4; ++i) {
        const int col = (ntb + w * 4 + i) * 16 + (lane & 15);
        const float bj = bias[col];
#pragma unroll
        for (int m = 0; m < 4; ++m)
#pragma unroll
            for (int r = 0; r < 4; ++r) {
                const int row = bm + m * 16 + ((lane >> 4) << 2) + r;
                C1[(size_t)row * 512 + col] = fmaxf(acc[m][i][r] + bj, 0.f);
            }
    }
}

// ---------------------------------------------------------------------------
// Fused cell stages 2+3: XC[:,256:384] = (relu(C1@Wr2+br2)) @ Wr3 + br3.
// 32-row blocks (grid 256), T staged split in LDS. ~39 KB -> 4 blocks/CU.
// ---------------------------------------------------------------------------
__global__ __launch_bounds__(256) void cell_s23(
    const float* __restrict__ C1,                          // [8192][512]
    const unsigned short* __restrict__ B2h, const unsigned short* __restrict__ B2l,  // Wr2 KS=16 NT=16
    const unsigned short* __restrict__ B3h, const unsigned short* __restrict__ B3l,  // Wr3 KS=8  NT=8
    const float* __restrict__ br2, const float* __restrict__ br3,
    float* __restrict__ XC)
{
    __shared__ unsigned short Ahs[32 * 40], Als[32 * 40];
    __shared__ unsigned short Th[32 * 264], Tl[32 * 264];
    const int tid = threadIdx.x, lane = tid & 63, w = tid >> 6;
    const int bm = blockIdx.x * 32;
    const int l15 = lane & 15, g8 = (lane >> 4) << 3, g4 = (lane >> 4) << 2;
    const int l8 = lane << 3;

    // ---- stage 1: T = relu(C1 @ Wr2 + br2), K=512 (KS=16), N=256 (16 tiles)
    f32x4 acc[2][4];
#pragma unroll
    for (int m = 0; m < 2; ++m)
#pragma unroll
        for (int i = 0; i < 4; ++i) acc[m][i] = (f32x4){0.f, 0.f, 0.f, 0.f};
    for (int ks = 0; ks < 16; ++ks) {
        __syncthreads();
        for (int idx = tid; idx < 256; idx += 256) {       // 1 float4 each
            const int row = idx >> 3, f4 = idx & 7;
            const int k = ks * 32 + f4 * 4;                // K=512 exact
            const float4 v = *(const float4*)(C1 + (size_t)(bm + row) * 512 + k);
            unsigned h01, l01, h23, l23;
            split_pair(v.x, v.y, h01, l01);
            split_pair(v.z, v.w, h23, l23);
            *(uint2*)(Ahs + row * 40 + f4 * 4) = make_uint2(h01, h23);
            *(uint2*)(Als + row * 40 + f4 * 4) = make_uint2(l01, l23);
        }
        __syncthreads();
        bf16x8 ah[2], al[2];
#pragma unroll
        for (int m = 0; m < 2; ++m) {
            const int off = (m * 16 + l15) * 40 + g8;
            ah[m] = *(const bf16x8*)(Ahs + off);
            al[m] = *(const bf16x8*)(Als + off);
        }
#pragma unroll
        for (int i = 0; i < 4; ++i) {
            const int nt = w + 4 * i;
            const int bo_ = ((nt * 16 + ks) << 9) + l8;
            const bf16x8 bh = *(const bf16x8*)(B2h + bo_);
            const bf16x8 bl = *(const bf16x8*)(B2l + bo_);
#pragma unroll
            for (int m = 0; m < 2; ++m) {
                acc[m][i] = __builtin_amdgcn_mfma_f32_16x16x32_bf16(ah[m], bh, acc[m][i], 0, 0, 0);
                acc[m][i] = __builtin_amdgcn_mfma_f32_16x16x32_bf16(al[m], bh, acc[m][i], 0, 0, 0);
                acc[m][i] = __builtin_amdgcn_mfma_f32_16x16x32_bf16(ah[m], bl, acc[m][i], 0, 0, 0);
            }
        }
    }
#pragma unroll
    for (int i = 0; i < 4; ++i) {
        const int col = (w + 4 * i) * 16 + l15;
        const float bj = br2[col];
#pragma unroll
        for (int m = 0; m < 2; ++m)
#pragma unroll
            for (int r = 0; r < 4; ++r) {
                const int row = m * 16 + g4 + r;
                const float v = fmaxf(acc[m][i][r] + bj, 0.f);
                unsigned short h, l; split2(v, h, l);
                Th[row * 264 + col] = h;
                Tl[row * 264 + col] = l;
            }
    }
    __syncthreads();

    // ---- stage 2: XC[:,256+] = T @ Wr3 + br3, K=256 (KS=8), N=128 (8 tiles)
    f32x4 acc2[2][2];
#pragma unroll
    for (int m = 0; m < 2; ++m)
#pragma unroll
        for (int i = 0; i < 2; ++i) acc2[m][i] = (f32x4){0.f, 0.f, 0.f, 0.f};
#pragma unroll
    for (int ks = 0; ks < 8; ++ks) {
        bf16x8 ah[2], al[2];
#pragma unroll
        for (int m = 0; m < 2; ++m) {
            const int off = (m * 16 + l15) * 264 + ks * 32 + g8;
            ah[m] = *(const bf16x8*)(Th + off);
            al[m] = *(const bf16x8*)(Tl + off);
        }
#pragma unroll
        for (int i = 0; i < 2; ++i) {
            const int nt = w + 4 * i;
            const int bo_ = ((nt * 8 + ks) << 9) + l8;
            const bf16x8 bh = *(const bf16x8*)(B3h + bo_);
            const bf16x8 bl = *(const bf16x8*)(B3l + bo_);
#pragma unroll
            for (int m = 0; m < 2; ++m) {
                acc2[m][i] = __builtin_amdgcn_mfma_f32_16x16x32_bf16(ah[m], bh, acc2[m][i], 0, 0, 0);
                acc2[m][i] = __builtin_amdgcn_mfma_f32_16x16x32_bf16(al[m], bh, acc2[m][i], 0, 0, 0);
                acc2[m][i] = __builtin_amdgcn_mfma_f32_16x16x32_bf16(ah[m], bl, acc2[m][i], 0, 0, 0);
            }
        }
    }
#pragma unroll
    for (int i = 0; i < 2; ++i) {
        const int col = (w + 4 * i) * 16 + l15;
        const float bj = br3[col];
#pragma unroll
        for (int m = 0; m < 2; ++m)
#pragma unroll
            for (int r = 0; r < 4; ++r) {
                const int row = bm + m * 16 + g4 + r;
                XC[(size_t)row * 384 + 256 + col] = acc2[m][i][r] + bj;
            }
    }
}

// ---------------------------------------------------------------------------
// Fused drug heads: XC[:,0:128 / 128:256] = (relu(G@Wg1+bg1)) @ Wg2 + bg2.
// ---------------------------------------------------------------------------
__global__ __launch_bounds__(256) void drughead(
    const float* __restrict__ G,                           // [16384][312]
    const unsigned short* __restrict__ B1h, const unsigned short* __restrict__ B1l,
    const unsigned short* __restrict__ B2h, const unsigned short* __restrict__ B2l,
    const float* __restrict__ bg1, const float* __restrict__ bg2,
    float* __restrict__ XC)
{
    __shared__ unsigned short Ahs[64 * 40], Als[64 * 40];
    __shared__ unsigned short Th[64 * 168], Tl[64 * 168];
    const int tid = threadIdx.x, lane = tid & 63, w = tid >> 6;
    const int bm = blockIdx.x * 64;
    const int l15 = lane & 15, g8 = (lane >> 4) << 3, g4 = (lane >> 4) << 2;
    const int l8 = lane << 3;

    // ---- stage 1: T = relu(G @ Wg1 + bg1), K=312 (KS=10), N=156 (10 tiles)
    f32x4 acc[4][3];
#pragma unroll
    for (int m = 0; m < 4; ++m)
#pragma unroll
        for (int i = 0; i < 3; ++i) acc[m][i] = (f32x4){0.f, 0.f, 0.f, 0.f};
    for (int ks = 0; ks < 10; ++ks) {
        __syncthreads();
        for (int idx = tid; idx < 512; idx += 256) {       // float4 staging
            const int row = idx >> 3, f4 = idx & 7;
            const int k = ks * 32 + f4 * 4;
            const float4 v = (k < 312) ? *(const float4*)(G + (size_t)(bm + row) * 312 + k)
                                       : make_float4(0.f, 0.f, 0.f, 0.f);
            unsigned h01, l01, h23, l23;
            split_pair(v.x, v.y, h01, l01);
            split_pair(v.z, v.w, h23, l23);
            *(uint2*)(Ahs + row * 40 + f4 * 4) = make_uint2(h01, h23);
            *(uint2*)(Als + row * 40 + f4 * 4) = make_uint2(l01, l23);
        }
        __syncthreads();
        bf16x8 ah[4], al[4];
#pragma unroll
        for (int m = 0; m < 4; ++m) {
            const int off = (m * 16 + l15) * 40 + g8;
            ah[m] = *(const bf16x8*)(Ahs + off);
            al[m] = *(const bf16x8*)(Als + off);
        }
#pragma unroll
        for (int i = 0; i < 3; ++i) {
            const int nt = w + 4 * i;
            if (nt < 10) {
                const int bo = ((nt * 10 + ks) << 9) + l8;
                const bf16x8 bh = *(const bf16x8*)(B1h + bo);
                const bf16x8 bl = *(const bf16x8*)(B1l + bo);
#pragma unroll
                for (int m = 0; m < 4; ++m) {
                    acc[m][i] = __builtin_amdgcn_mfma_f32_16x16x32_bf16(ah[m], bh, acc[m][i], 0, 0, 0);
                    acc[m][i] = __builtin_amdgcn_mfma_f32_16x16x32_bf16(al[m], bh, acc[m][i], 0, 0, 0);
                    acc[m][i] = __builtin_amdgcn_mfma_f32_16x16x32_bf16(ah[m], bl, acc[m][i], 0, 0, 0);
                }
            }
        }
    }
    // epi1: relu+bias, split -> T (cols 156..159 zeroed for NaN safety)
#pragma unroll
    for (int i = 0; i < 3; ++i) {
        const int nt = w + 4 * i;
        if (nt < 10) {
            const int col = nt * 16 + l15;
            const float bj = (col < 156) ? bg1[col] : 0.f;
#pragma unroll
            for (int m = 0; m < 4; ++m)
#pragma unroll
                for (int r = 0; r < 4; ++r) {
                    const int row = m * 16 + g4 + r;
                    float v = (col < 156) ? fmaxf(acc[m][i][r] + bj, 0.f) : 0.f;
                    unsigned short h, l; split2(v, h, l);
                    Th[row * 168 + col] = h;
                    Tl[row * 168 + col] = l;
                }
        }
    }
    __syncthreads();

    // ---- stage 2: XC cols = T @ Wg2 + bg2, K=156 (KS=5), N=128 (8 tiles)
    f32x4 acc2[4][2];
#pragma unroll
    for (int m = 0; m < 4; ++m)
#pragma unroll
        for (int i = 0; i < 2; ++i) acc2[m][i] = (f32x4){0.f, 0.f, 0.f, 0.f};
#pragma unroll
    for (int ks = 0; ks < 5; ++ks) {
        bf16x8 ah[4], al[4];
#pragma unroll
        for (int m = 0; m < 4; ++m) {
            const int off = (m * 16 + l15) * 168 + ks * 32 + g8;
            ah[m] = *(const bf16x8*)(Th + off);
            al[m] = *(const bf16x8*)(Tl + off);
        }
#pragma unroll
        for (int i = 0; i < 2; ++i) {
            const int nt = w + 4 * i;
            const int bo = ((nt * 5 + ks) << 9) + l8;
            const bf16x8 bh = *(const bf16x8*)(B2h + bo);
            const bf16x8 bl = *(const bf16x8*)(B2l + bo);
#pragma unroll
            for (int m = 0; m < 4; ++m) {
                acc2[m][i] = __builtin_amdgcn_mfma_f32_16x16x32_bf16(ah[m], bh, acc2[m][i], 0, 0, 0);
                acc2[m][i] = __builtin_amdgcn_mfma_f32_16x16x32_bf16(al[m], bh, acc2[m][i], 0, 0, 0);
                acc2[m][i] = __builtin_amdgcn_mfma_f32_16x16x32_bf16(ah[m], bl, acc2[m][i], 0, 0, 0);
            }
        }
    }
#pragma unroll
    for (int i = 0; i < 2; ++i) {
        const int col = (w + 4 * i) * 16 + l15;
        const float bj = bg2[col];
#pragma unroll
        for (int m = 0; m < 4; ++m)
#pragma unroll
            for (int r = 0; r < 4; ++r) {
                const int row = bm + m * 16 + g4 + r;
                const int crow = row & (BGRAPH - 1);
                const int cadd = (row >> 13) * 128;
                XC[(size_t)crow * 384 + cadd + col] = acc2[m][i][r] + bj;
            }
    }
}

// ---------------------------------------------------------------------------
// Fused head: out = (relu(relu(XC@Wf1+bf1)@Wf2+bf2)) @ Wo + bo.
// ---------------------------------------------------------------------------
__global__ __launch_bounds__(256) void head_fused(
    const float* __restrict__ XC,                          // [8192][384]
    const unsigned short* __restrict__ B1h, const unsigned short* __restrict__ B1l,
    const unsigned short* __restrict__ B2h, const unsigned short* __restrict__ B2l,
    const unsigned short* __restrict__ B3h, const unsigned short* __restrict__ B3l,
    const float* __restrict__ bf1, const float* __restrict__ bf2, const float* __restrict__ bo,
    float* __restrict__ out)
{
    __shared__ unsigned short Ahs[32 * 40], Als[32 * 40];
    __shared__ unsigned short T1h[32 * 280], T1l[32 * 280];
    unsigned short* T2h = T1h;                             // aliased, stride 136
    unsigned short* T2l = T1l;
    const int tid = threadIdx.x, lane = tid & 63, w = tid >> 6;
    const int bm = blockIdx.x * 32;
    const int l15 = lane & 15, g8 = (lane >> 4) << 3, g4 = (lane >> 4) << 2;
    const int l8 = lane << 3;

    // ---- stage 1: T1 = relu(XC @ Wf1 + bf1), K=384 (KS=12), N=256 (16 tiles)
    f32x4 acc[2][4];
#pragma unroll
    for (int m = 0; m < 2; ++m)
#pragma unroll
        for (int i = 0; i < 4; ++i) acc[m][i] = (f32x4){0.f, 0.f, 0.f, 0.f};
    for (int ks = 0; ks < 12; ++ks) {
        __syncthreads();
        for (int idx = tid; idx < 256; idx += 256) {       // 1 float4 each
            const int row = idx >> 3, f4 = idx & 7;
            const int k = ks * 32 + f4 * 4;                // K=384 exact
            const float4 v = *(const float4*)(XC + (size_t)(bm + row) * 384 + k);
            unsigned h01, l01, h23, l23;
            split_pair(v.x, v.y, h01, l01);
            split_pair(v.z, v.w, h23, l23);
            *(uint2*)(Ahs + row * 40 + f4 * 4) = make_uint2(h01, h23);
            *(uint2*)(Als + row * 40 + f4 * 4) = make_uint2(l01, l23);
        }
        __syncthreads();
        bf16x8 ah[2], al[2];
#pragma unroll
        for (int m = 0; m < 2; ++m) {
            const int off = (m * 16 + l15) * 40 + g8;
            ah[m] = *(const bf16x8*)(Ahs + off);
            al[m] = *(const bf16x8*)(Als + off);
        }
#pragma unroll
        for (int i = 0; i < 4; ++i) {
            const int nt = w + 4 * i;
            const int bo_ = ((nt * 12 + ks) << 9) + l8;
            const bf16x8 bh = *(const bf16x8*)(B1h + bo_);
            const bf16x8 bl = *(const bf16x8*)(B1l + bo_);
#pragma unroll
            for (int m = 0; m < 2; ++m) {
                acc[m][i] = __builtin_amdgcn_mfma_f32_16x16x32_bf16(ah[m], bh, acc[m][i], 0, 0, 0);
                acc[m][i] = __builtin_amdgcn_mfma_f32_16x16x32_bf16(al[m], bh, acc[m][i], 0, 0, 0);
                acc[m][i] = __builtin_amdgcn_mfma_f32_16x16x32_bf16(ah[m], bl, acc[m][i], 0, 0, 0);
            }
        }
    }
#pragma unroll
    for (int i = 0; i < 4; ++i) {
        const int col = (w + 4 * i) * 16 + l15;
        const float bj = bf1[col];
#pragma unroll
        for (int m = 0; m < 2; ++m)
#pragma unroll
            for (int r = 0; r < 4; ++r) {
                const int row = m * 16 + g4 + r;
                const float v = fmaxf(acc[m][i][r] + bj, 0.f);
                unsigned short h, l; split2(v, h, l);
                T1h[row * 280 + col] = h;
                T1l[row * 280 + col] = l;
            }
    }
    __syncthreads();

    // ---- stage 2: T2 = relu(T1 @ Wf2 + bf2), K=256 (KS=8), N=128 (8 tiles)
    f32x4 acc2[2][2];
#pragma unroll
    for (int m = 0; m < 2; ++m)
#pragma unroll
        for (int i = 0; i < 2; ++i) acc2[m][i] = (f32x4){0.f, 0.f, 0.f, 0.f};
#pragma unroll
    for (int ks = 0; ks < 8; ++ks) {
        bf16x8 ah[2], al[2];
#pragma unroll
        for (int m = 0; m < 2; ++m) {
            const int off = (m * 16 + l15) * 280 + ks * 32 + g8;
            ah[m] = *(const bf16x8*)(T1h + off);
            al[m] = *(const bf16x8*)(T1l + off);
        }
#pragma unroll
        for (int i = 0; i < 2; ++i) {
            const int nt = w + 4 * i;
            const int bo_ = ((nt * 8 + ks) << 9) + l8;
            const bf16x8 bh = *(const bf16x8*)(B2h + bo_);
            const bf16x8 bl = *(const bf16x8*)(B2l + bo_);
#pragma unroll
            for (int m = 0; m < 2; ++m) {
                acc2[m][i] = __builtin_amdgcn_mfma_f32_16x16x32_bf16(ah[m], bh, acc2[m][i], 0, 0, 0);
                acc2[m][i] = __builtin_amdgcn_mfma_f32_16x16x32_bf16(al[m], bh, acc2[m][i], 0, 0, 0);
                acc2[m][i] = __builtin_amdgcn_mfma_f32_16x16x32_bf16(ah[m], bl, acc2[m][i], 0, 0, 0);
            }
        }
    }
    __syncthreads();                       // all T1 reads done (T2 aliases T1)
#pragma unroll
    for (int i = 0; i < 2; ++i) {
        const int col = (w + 4 * i) * 16 + l15;
        const float bj = bf2[col];
#pragma unroll
        for (int m = 0; m < 2; ++m)
#pragma unroll
            for (int r = 0; r < 4; ++r) {
                const int row = m * 16 + g4 + r;
                const float v = fmaxf(acc2[m][i][r] + bj, 0.f);
                unsigned short h, l; split2(v, h, l);
                T2h[row * 136 + col] = h;
                T2l[row * 136 + col] = l;
            }
    }
    __syncthreads();

    // ---- stage 3: out = T2 @ Wo + bo, K=128 (KS=4), N=2 (tile 0, wave 0)
    if (w == 0) {
        f32x4 acc3[2];
        acc3[0] = (f32x4){0.f, 0.f, 0.f, 0.f};
        acc3[1] = (f32x4){0.f, 0.f, 0.f, 0.f};
#pragma unroll
        for (int ks = 0; ks < 4; ++ks) {
            bf16x8 ah[2], al[2];
#pragma unroll
            for (int m = 0; m < 2; ++m) {
                const int off = (m * 16 + l15) * 136 + ks * 32 + g8;
                ah[m] = *(const bf16x8*)(T2h + off);
                al[m] = *(const bf16x8*)(T2l + off);
            }
            const int bo_ = (ks << 9) + l8;
            const bf16x8 bh = *(const bf16x8*)(B3h + bo_);
            const bf16x8 bl = *(const bf16x8*)(B3l + bo_);
#pragma unroll
            for (int m = 0; m < 2; ++m) {
                acc3[m] = __builtin_amdgcn_mfma_f32_16x16x32_bf16(ah[m], bh, acc3[m], 0, 0, 0);
                acc3[m] = __builtin_amdgcn_mfma_f32_16x16x32_bf16(al[m], bh, acc3[m], 0, 0, 0);
                acc3[m] = __builtin_amdgcn_mfma_f32_16x16x32_bf16(ah[m], bl, acc3[m], 0, 0, 0);
            }
        }
        if (l15 < 2) {
            const float bj = bo[l15];
#pragma unroll
            for (int m = 0; m < 2; ++m)
#pragma unroll
                for (int r = 0; r < 4; ++r)
                    out[(size_t)(bm + m * 16 + g4 + r) * 2 + l15] = acc3[m][r] + bj;
        }
    }
}

// ---------------------------------------------------------------------------

extern "C" void kernel_launch(void* const* d_in, const int* in_sizes, int n_in,
                              void* d_out, int out_size, void* d_ws, size_t ws_size,
                              hipStream_t stream)
{
    (void)in_sizes; (void)n_in; (void)out_size; (void)ws_size;
    const float* x1   = (const float*)d_in[0];
    const int*   ei1  = (const int*)d_in[1];
    const float* x2   = (const float*)d_in[3];
    const int*   ei2  = (const int*)d_in[4];
    const float* cell = (const float*)d_in[6];
    const float* Wc1 = (const float*)d_in[7],  *bc1 = (const float*)d_in[8];
    const float* Wc2 = (const float*)d_in[9],  *bc2 = (const float*)d_in[10];
    const float* Wc3 = (const float*)d_in[11], *bc3 = (const float*)d_in[12];
    const float* Wg1 = (const float*)d_in[13], *bg1 = (const float*)d_in[14];
    const float* Wg2 = (const float*)d_in[15], *bg2 = (const float*)d_in[16];
    const float* Wr1 = (const float*)d_in[17], *br1 = (const float*)d_in[18];
    const float* Wr2 = (const float*)d_in[19], *br2 = (const float*)d_in[20];
    const float* Wr3 = (const float*)d_in[21], *br3 = (const float*)d_in[22];
    const float* Wf1 = (const float*)d_in[23], *bf1 = (const float*)d_in[24];
    const float* Wf2 = (const float*)d_in[25], *bf2 = (const float*)d_in[26];
    const float* Wo  = (const float*)d_in[27], *bo  = (const float*)d_in[28];
    float* out = (float*)d_out;
    float* ws  = (float*)d_ws;

    size_t o = 0;
    auto allocF = [&](size_t n) { float* p = ws + o; o += n; return p; };
    auto allocU = [&](size_t n) { unsigned short* p = (unsigned short*)(ws + o); o += n / 2; return p; };

    float* G1  = allocF((size_t)2 * BGRAPH * 312);   // both branches stacked
    float* C1  = allocF((size_t)BGRAPH * 512);
    float* XC  = allocF((size_t)BGRAPH * 384);

    // swizzled split weights (ushort counts = NT*KS*512)
    const int sWc1 = 8  * 3  * 512, sWc2 = 12 * 3  * 512, sWc3 = 20 * 5  * 512;
    const int sWg1 = 10 * 10 * 512, sWg2 = 8  * 5  * 512;
    const int sWr1 = 32 * 30 * 512, sWr2 = 16 * 16 * 512, sWr3 = 8 * 8 * 512;
    const int sWf1 = 16 * 12 * 512, sWf2 = 8  * 8  * 512, sWoo = 1 * 4 * 512;
    unsigned short *Wc1h = allocU(sWc1), *Wc1l = allocU(sWc1);
    unsigned short *Wc2h = allocU(sWc2), *Wc2l = allocU(sWc2);
    unsigned short *Wc3h = allocU(sWc3), *Wc3l = allocU(sWc3);
    unsigned short *Wg1h = allocU(sWg1), *Wg1l = allocU(sWg1);
    unsigned short *Wg2h = allocU(sWg2), *Wg2l = allocU(sWg2);
    unsigned short *Wr1h = allocU(sWr1), *Wr1l = allocU(sWr1);
    unsigned short *Wr2h = allocU(sWr2), *Wr2l = allocU(sWr2);
    unsigned short *Wr3h = allocU(sWr3), *Wr3l = allocU(sWr3);
    unsigned short *Wf1h = allocU(sWf1), *Wf1l = allocU(sWf1);
    unsigned short *Wf2h = allocU(sWf2), *Wf2l = allocU(sWf2);
    unsigned short *Wooh = allocU(sWoo), *Wool = allocU(sWoo);

    // one fused weight-prep launch
    WTab tab;
    int base = 0, ti = 0;
    auto addw = [&](const float* W, int K, int N, int KS, int NT,
                    unsigned short* Bh, unsigned short* Bl) {
        tab.d[ti] = WDesc{W, Bh, Bl, K, N, KS, NT, base};
        base += NT * KS * 2;              // blocks = NT*KS*512/256
        ++ti;
    };
    addw(Wc1, 78, 78, 3, 8, Wc1h, Wc1l);
    addw(Wc2, 78, 156, 3, 12, Wc2h, Wc2l);
    addw(Wc3, 156, 312, 5, 20, Wc3h, Wc3l);
    addw(Wg1, 312, 156, 10, 10, Wg1h, Wg1l);
    addw(Wg2, 156, 128, 5, 8, Wg2h, Wg2l);
    addw(Wr1, 954, 512, 30, 32, Wr1h, Wr1l);
    addw(Wr2, 512, 256, 16, 16, Wr2h, Wr2l);
    addw(Wr3, 256, 128, 8, 8, Wr3h, Wr3l);
    addw(Wf1, 384, 256, 12, 16, Wf1h, Wf1l);
    addw(Wf2, 256, 128, 8, 8, Wf2h, Wf2l);
    addw(Wo,  128, 2,   4, 1, Wooh, Wool);
    wprep_all<<<base, 256, 0, stream>>>(tab);

    // both drug branches (GCN x3 + maxpool) in one launch; G2 follows G1
    gcn_graph<<<2 * BGRAPH, GT, 0, stream>>>(x1, ei1, x2, ei2,
        Wc1h, Wc1l, Wc2h, Wc2l, Wc3h, Wc3l, bc1, bc2, bc3, G1);

    // fused drug heads (M = 16384): G -> XC[:,0:128] / [:,128:256]
    drughead<<<256, 256, 0, stream>>>(G1, Wg1h, Wg1l, Wg2h, Wg2l, bg1, bg2, XC);

    // cell MLP -> XC[:,256:384] (stage 1 fuses the L2 normalize; 2+3 fused)
    cell_s1<<<dim3(128, 2), 256, 0, stream>>>(cell, Wr1h, Wr1l, br1, C1);
    cell_s23<<<256, 256, 0, stream>>>(C1, Wr2h, Wr2l, Wr3h, Wr3l, br2, br3, XC);

    // fused head: XC -> out
    head_fused<<<256, 256, 0, stream>>>(XC, Wf1h, Wf1l, Wf2h, Wf2l, Wooh, Wool,
                                        bf1, bf2, bo, out);
}

// Round 12
// 744.228 us; speedup vs baseline: 1.5719x; 1.2616x over previous
//
#include <hip/hip_runtime.h>
#include <math.h>

#define EE 819200          // edges total
#define BGRAPH 8192        // graphs
constexpr int GT = 512;    // threads, graph kernel (8 waves)

typedef __attribute__((ext_vector_type(8))) short bf16x8;   // 4 VGPRs = 8 bf16
typedef __attribute__((ext_vector_type(4))) float f32x4;

// ---- fp32 -> bf16 split (RNE), a ~= hi + lo, |a-(hi+lo)| <= 2^-18 |a| ----
__device__ inline unsigned short f2bf(float x) {
    unsigned u = __float_as_uint(x);
    u += 0x7fffu + ((u >> 16) & 1u);
    return (unsigned short)(u >> 16);
}
__device__ inline float bf2f(unsigned short h) {
    return __uint_as_float(((unsigned)h) << 16);
}
__device__ inline void split2(float v, unsigned short& hi, unsigned short& lo) {
    hi = f2bf(v);
    lo = f2bf(v - bf2f(hi));
}
// packed RNE split of a value-pair: h = {bf16(b)|bf16(a)}, l = residuals
__device__ inline unsigned cvtpk_bf16(float a, float b) {
    unsigned r;
    asm("v_cvt_pk_bf16_f32 %0, %1, %2" : "=v"(r) : "v"(a), "v"(b));
    return r;
}
__device__ inline void split_pair(float a, float b, unsigned& h, unsigned& l) {
    h = cvtpk_bf16(a, b);
    const float ra = a - __uint_as_float(h << 16);
    const float rb = b - __uint_as_float(h & 0xffff0000u);
    l = cvtpk_bf16(ra, rb);
}

// ---------------------------------------------------------------------------
// Fused weight prep (one launch): W[K][N] fp32 -> fragment-ordered hi/lo bf16,
// zero-padded to (KS*32) x (NT*16).
// ---------------------------------------------------------------------------
struct WDesc { const float* W; unsigned short* Bh; unsigned short* Bl;
               int K, N, KS, NT, base; };
struct WTab { WDesc d[11]; };

__global__ __launch_bounds__(256) void wprep_all(WTab tab)
{
    const int bid = blockIdx.x;
    int t = 0;
#pragma unroll
    for (int i = 1; i < 11; ++i) if (bid >= tab.d[i].base) t = i;
    const WDesc D = tab.d[t];
    const int idx = (bid - D.base) * 256 + (int)threadIdx.x;
    if (idx >= D.NT * D.KS * 512) return;
    const int r    = idx & 7;
    const int lane = (idx >> 3) & 63;
    const int rest = idx >> 9;
    const int ks   = rest % D.KS;
    const int nt   = rest / D.KS;
    const int k = ks * 32 + ((lane >> 4) << 3) + r;
    const int n = nt * 16 + (lane & 15);
    const float v = (k < D.K && n < D.N) ? D.W[(size_t)k * D.N + n] : 0.f;
    unsigned short h, l; split2(v, h, l);
    D.Bh[idx] = h; D.Bl[idx] = l;
}

// ---------------------------------------------------------------------------
// Per-graph fused 3-layer GCN + max pool, bf16x3 MFMA (R9/R11 structure).
// act fp32 [50][164] (odd float4 stride). Frags [50][168] hi/lo.
// ---------------------------------------------------------------------------

template<int KS, int NI, int FOUT>   // K-steps; n-tiles/wave; real out cols
__device__ inline void layer_run(const unsigned short* __restrict__ Bh,
                                 const unsigned short* __restrict__ Bl,
                                 const unsigned short* Ah, const unsigned short* Al,
                                 f32x4 (&acc)[2][5], int mg, int ng, int lane)
{
#pragma unroll
    for (int m = 0; m < 2; ++m)
#pragma unroll
        for (int i = 0; i < NI; ++i) acc[m][i] = (f32x4){0.f, 0.f, 0.f, 0.f};
    const int g8 = (lane >> 4) << 3;
    const int l8 = lane << 3;
#pragma unroll
    for (int ks = 0; ks < KS; ++ks) {
        bf16x8 ah[2], al[2];
#pragma unroll
        for (int m = 0; m < 2; ++m) {
            const int off = (mg * 32 + m * 16 + (lane & 15)) * 168 + ks * 32 + g8;
            ah[m] = *(const bf16x8*)(Ah + off);
            al[m] = *(const bf16x8*)(Al + off);
        }
#pragma unroll
        for (int i = 0; i < NI; ++i) {
            const int nt = ng + (i << 2);
            if (nt * 16 < FOUT) {              // skip all-zero W tiles (uniform)
                const int bo = ((nt * KS + ks) << 9) + l8;
                const bf16x8 bh = *(const bf16x8*)(Bh + bo);
                const bf16x8 bl = *(const bf16x8*)(Bl + bo);
#pragma unroll
                for (int m = 0; m < 2; ++m) {
                    acc[m][i] = __builtin_amdgcn_mfma_f32_16x16x32_bf16(ah[m], bh, acc[m][i], 0, 0, 0);
                    acc[m][i] = __builtin_amdgcn_mfma_f32_16x16x32_bf16(al[m], bh, acc[m][i], 0, 0, 0);
                    acc[m][i] = __builtin_amdgcn_mfma_f32_16x16x32_bf16(ah[m], bl, acc[m][i], 0, 0, 0);
                }
            }
        }
    }
}

// D layout: col = lane&15 (+16*nt), row = (lane>>4)*4 + reg (+16*mt)
template<int NI, int NCOL>
__device__ inline void epi_store(const f32x4 (&acc)[2][5], const float* __restrict__ bias,
                                 float* act, int mg, int ng, int lane)
{
#pragma unroll
    for (int i = 0; i < NI; ++i) {
        const int col = (ng + (i << 2)) * 16 + (lane & 15);
        if (col < NCOL) {
            const float bj = bias[col];
#pragma unroll
            for (int m = 0; m < 2; ++m)
#pragma unroll
                for (int r = 0; r < 4; ++r) {
                    const int row = mg * 32 + m * 16 + ((lane >> 4) << 2) + r;
                    if (row < 50)
                        act[row * 164 + col] = fmaxf(acc[m][i][r] + bj, 0.f);
                }
        }
    }
}

__device__ inline void pool_store(const f32x4 (&acc)[2][5], const float* __restrict__ bias,
                                  unsigned* gmax, int mg, int ng, int lane)
{
#pragma unroll
    for (int i = 0; i < 5; ++i) {
        const int col = (ng + (i << 2)) * 16 + (lane & 15);
        const float bj = (col < 312) ? bias[col] : 0.f;
        float m = 0.f;                      // relu floor == pool identity
#pragma unroll
        for (int mm = 0; mm < 2; ++mm)
#pragma unroll
            for (int r = 0; r < 4; ++r) {
                const int row = mg * 32 + mm * 16 + ((lane >> 4) << 2) + r;
                if (row < 50) m = fmaxf(m, acc[mm][i][r] + bj);
            }
        m = fmaxf(m, __shfl_xor(m, 16, 64));
        m = fmaxf(m, __shfl_xor(m, 32, 64));
        if (lane < 16 && col < 312)
            atomicMax(&gmax[col], __float_as_uint(m));
    }
}

// agg (Â·H) fused with bf16-split, 8 features/item (two float4 chains),
// edge-pair unrolling, cvt_pk RNE splits, b128 stores. act4 stride 41 (odd).
template<int NCOL>
__device__ inline void agg_split8(const float4* __restrict__ act4,
                                  unsigned short* Ah, unsigned short* Al,
                                  const int* insrc, const float* insn,
                                  const int* inoff, const float* selfw, int tid)
{
    constexpr int CH = (NCOL + 7) / 8;     // 8-float chunks per row (pads zero)
    for (int idx = tid; idx < 50 * CH; idx += GT) {
        const int n = idx / CH;            // constexpr divisor -> magic-mul
        const int c2 = (idx - n * CH) * 2; // float4 index within row
        const float sw = selfw[n];
        const float4 v0 = act4[n * 41 + c2];
        const float4 v1 = act4[n * 41 + c2 + 1];
        float4 a0, a1;
        a0.x = sw * v0.x; a0.y = sw * v0.y; a0.z = sw * v0.z; a0.w = sw * v0.w;
        a1.x = sw * v1.x; a1.y = sw * v1.y; a1.z = sw * v1.z; a1.w = sw * v1.w;
        int j = inoff[n];
        const int j1 = inoff[n + 1];
        for (; j + 1 < j1; j += 2) {
            const int s0 = insrc[j] * 41 + c2;
            const int s1 = insrc[j + 1] * 41 + c2;
            const float w0 = insn[j], w1 = insn[j + 1];
            const float4 e00 = act4[s0], e01 = act4[s0 + 1];
            const float4 e10 = act4[s1], e11 = act4[s1 + 1];
            a0.x = fmaf(w1, e10.x, fmaf(w0, e00.x, a0.x));
            a0.y = fmaf(w1, e10.y, fmaf(w0, e00.y, a0.y));
            a0.z = fmaf(w1, e10.z, fmaf(w0, e00.z, a0.z));
            a0.w = fmaf(w1, e10.w, fmaf(w0, e00.w, a0.w));
            a1.x = fmaf(w1, e11.x, fmaf(w0, e01.x, a1.x));
            a1.y = fmaf(w1, e11.y, fmaf(w0, e01.y, a1.y));
            a1.z = fmaf(w1, e11.z, fmaf(w0, e01.z, a1.z));
            a1.w = fmaf(w1, e11.w, fmaf(w0, e01.w, a1.w));
        }
        if (j < j1) {
            const int s0 = insrc[j] * 41 + c2;
            const float w0 = insn[j];
            const float4 e00 = act4[s0], e01 = act4[s0 + 1];
            a0.x = fmaf(w0, e00.x, a0.x);
            a0.y = fmaf(w0, e00.y, a0.y);
            a0.z = fmaf(w0, e00.z, a0.z);
            a0.w = fmaf(w0, e00.w, a0.w);
            a1.x = fmaf(w0, e01.x, a1.x);
            a1.y = fmaf(w0, e01.y, a1.y);
            a1.z = fmaf(w0, e01.z, a1.z);
            a1.w = fmaf(w0, e01.w, a1.w);
        }
        unsigned h01, h23, h45, h67, l01, l23, l45, l67;
        split_pair(a0.x, a0.y, h01, l01);
        split_pair(a0.z, a0.w, h23, l23);
        split_pair(a1.x, a1.y, h45, l45);
        split_pair(a1.z, a1.w, h67, l67);
        const int off = n * 168 + (c2 << 2);           // 16B-aligned
        *(uint4*)(Ah + off) = make_uint4(h01, h23, h45, h67);
        *(uint4*)(Al + off) = make_uint4(l01, l23, l45, l67);
    }
}

__global__ __launch_bounds__(GT, 4) void gcn_graph(
    const float* __restrict__ x1, const int* __restrict__ ei1,
    const float* __restrict__ x2, const int* __restrict__ ei2,
    const unsigned short* __restrict__ W1h, const unsigned short* __restrict__ W1l,
    const unsigned short* __restrict__ W2h, const unsigned short* __restrict__ W2l,
    const unsigned short* __restrict__ W3h, const unsigned short* __restrict__ W3l,
    const float* __restrict__ bc1, const float* __restrict__ bc2, const float* __restrict__ bc3,
    float* __restrict__ G)              // [2*B,312]
{
    __shared__ __align__(16) unsigned short Ah[50 * 168], Al[50 * 168];
    __shared__ float4 act4s[50 * 41];                       // fp32 act [50][164]
    __shared__ int   es[100], ed[100], insrc[100];
    __shared__ float insn[100];
    __shared__ int   inoff[51], cnt[50], cnt2[50];
    __shared__ float dinvs[50], selfw[50];
    __shared__ unsigned gmax[312];

    const int br = blockIdx.x >> 13;
    const int b  = blockIdx.x & (BGRAPH - 1);
    const float* X    = br ? x2 : x1;
    const int*   srcA = br ? ei2 : ei1;
    const int*   dstA = srcA + EE;
    const int nb = b * 50, eb = b * 100, tid = threadIdx.x;
    const int lane = tid & 63;
    const int w = tid >> 6;
    const int mg = w >> 2, ng = w & 3;
    float* act = (float*)act4s;
    const float4* act4 = act4s;

    // ---- P1: X -> LDS directly (cols 0..77; disjoint from zero bands),
    //          zero only what must be zero, load edges
    for (int idx = tid; idx < 3900; idx += GT) {            // fully coalesced
        const int n = idx / 78, c = idx - n * 78;
        act[n * 164 + c] = X[(size_t)nb * 78 + idx];
    }
    // act zero bands: cols 78,79 (L1/L2 agg tail) + 156..159 (L3 agg tail)
    for (int i = tid; i < 300; i += GT) {
        const int n = i / 6, j = i - 6 * n;
        act[n * 164 + (j < 2 ? 78 + j : 154 + j)] = 0.f;
    }
    // frag k-band cols 80..95 rows 0..49 (NaN safety: L1/L2 write cols<80,
    // ks=2 reads k 64..95; W zero-pad nullifies VALUE but not NaN garbage)
    for (int i = tid; i < 50 * 8; i += GT) {
        const int n = i >> 3, c = ((i & 7) << 1) + 80;
        *(unsigned*)(Ah + n * 168 + c) = 0u;
        *(unsigned*)(Al + n * 168 + c) = 0u;
    }
    for (int i = tid; i < 312; i += GT) gmax[i] = 0u;
    for (int i = tid; i < 50; i += GT) { cnt[i] = 0; cnt2[i] = 0; }
    for (int e = tid; e < 100; e += GT) { es[e] = srcA[eb + e] - nb; ed[e] = dstA[eb + e] - nb; }
    __syncthreads();
    // ---- P2: degree count
    for (int e = tid; e < 100; e += GT) atomicAdd(&cnt[ed[e]], 1);
    __syncthreads();
    // ---- P3: dinv/selfw (parallel) + serial prefix (tid 0)
    for (int n = tid; n < 50; n += GT) {
        const float dv = 1.0f / sqrtf((float)cnt[n] + 1.0f);
        dinvs[n] = dv; selfw[n] = dv * dv;
    }
    if (tid == 0) { int off = 0; for (int n = 0; n < 50; ++n) { inoff[n] = off; off += cnt[n]; } inoff[50] = off; }
    __syncthreads();
    // ---- P4: counting sort (cnt2)
    for (int e = tid; e < 100; e += GT) {
        const int d = ed[e];
        const int p = inoff[d] + atomicAdd(&cnt2[d], 1);
        insrc[p] = es[e];
        insn[p]  = dinvs[es[e]] * dinvs[d];
    }
    __syncthreads();

    f32x4 acc[2][5];

    // layer 1: agg(X) -> 78x78
    agg_split8<78>(act4, Ah, Al, insrc, insn, inoff, selfw, tid);
    __syncthreads();
    __builtin_amdgcn_s_setprio(1);
    layer_run<3, 2, 78>(W1h, W1l, Ah, Al, acc, mg, ng, lane);
    __builtin_amdgcn_s_setprio(0);
    epi_store<2, 78>(acc, bc1, act, mg, ng, lane);
    __syncthreads();

    // layer 2: agg -> 78x156
    agg_split8<78>(act4, Ah, Al, insrc, insn, inoff, selfw, tid);
    __syncthreads();
    __builtin_amdgcn_s_setprio(1);
    layer_run<3, 3, 156>(W2h, W2l, Ah, Al, acc, mg, ng, lane);
    __builtin_amdgcn_s_setprio(0);
    epi_store<3, 156>(acc, bc2, act, mg, ng, lane);
    __syncthreads();

    // layer 3: agg -> 156x312 + fused bias/relu/maxpool
    agg_split8<156>(act4, Ah, Al, insrc, insn, inoff, selfw, tid);
    __syncthreads();
    __builtin_amdgcn_s_setprio(1);
    layer_run<5, 5, 312>(W3h, W3l, Ah, Al, acc, mg, ng, lane);
    __builtin_amdgcn_s_setprio(0);
    pool_store(acc, bc3, gmax, mg, ng, lane);
    __syncthreads();
    for (int f = tid; f < 312; f += GT)
        G[(size_t)(br * BGRAPH + b) * 312 + f] = __uint_as_float(gmax[f]);
}

// ---------------------------------------------------------------------------
// Cell stage 1 with fused L2-normalize: C1 = relu(norm(cell) @ Wr1 + br1).
// 512 threads (8 waves, 2/SIMD): wave w owns n-tiles ntb + 2w + i.
// ---------------------------------------------------------------------------
__global__ __launch_bounds__(512) void cell_s1(
    const float* __restrict__ cell,                       // [8192][954]
    const unsigned short* __restrict__ Bh, const unsigned short* __restrict__ Bl,
    const float* __restrict__ bias, float* __restrict__ C1)
{
    __shared__ unsigned short Ahs[64 * 40], Als[64 * 40];
    __shared__ float rn[64];
    const int tid = threadIdx.x, lane = tid & 63, w = tid >> 6;
    const int bm = blockIdx.x * 64;
    const int ntb = blockIdx.y * 16;
    const int g8 = (lane >> 4) << 3;
    const int l8 = lane << 3;

    if (tid < 64) rn[tid] = 0.f;
    __syncthreads();
    {
        const int row = tid & 63, part = tid >> 6;        // 8 partials/row
        float ss = 0.f;
        for (int c = part; c < 954; c += 8) {
            const float v = cell[(size_t)(bm + row) * 954 + c];
            ss = fmaf(v, v, ss);
        }
        atomicAdd(&rn[row], ss);
    }
    __syncthreads();
    if (tid < 64) rn[tid] = 1.0f / fmaxf(sqrtf(rn[tid]), 1e-12f);

    f32x4 acc[4][2];
#pragma unroll
    for (int m = 0; m < 4; ++m)
#pragma unroll
        for (int i = 0; i < 2; ++i) acc[m][i] = (f32x4){0.f, 0.f, 0.f, 0.f};

    for (int ks = 0; ks < 30; ++ks) {
        __syncthreads();
        for (int idx = tid; idx < 1024; idx += 512) {
            const int row = idx >> 4, p = idx & 15;
            const int k = ks * 32 + p * 2;
            float2 v = (k < 954) ? *(const float2*)(cell + (size_t)(bm + row) * 954 + k)
                                 : make_float2(0.f, 0.f);
            const float rr = rn[row];
            unsigned h, l; split_pair(v.x * rr, v.y * rr, h, l);
            *(unsigned*)(Ahs + row * 40 + p * 2) = h;
            *(unsigned*)(Als + row * 40 + p * 2) = l;
        }
        __syncthreads();
        bf16x8 ah[4], al[4];
#pragma unroll
        for (int m = 0; m < 4; ++m) {
            const int off = (m * 16 + (lane & 15)) * 40 + g8;
            ah[m] = *(const bf16x8*)(Ahs + off);
            al[m] = *(const bf16x8*)(Als + off);
        }
#pragma unroll
        for (int i = 0; i < 2; ++i) {
            const int nt = ntb + w * 2 + i;
            const int bo = ((nt * 30 + ks) << 9) + l8;
            const bf16x8 bh = *(const bf16x8*)(Bh + bo);
            const bf16x8 bl = *(const bf16x8*)(Bl + bo);
#pragma unroll
            for (int m = 0; m < 4; ++m) {
                acc[m][i] = __builtin_amdgcn_mfma_f32_16x16x32_bf16(ah[m], bh, acc[m][i], 0, 0, 0);
                acc[m][i] = __builtin_amdgcn_mfma_f32_16x16x32_bf16(al[m], bh, acc[m][i], 0, 0, 0);
                acc[m][i] = __builtin_amdgcn_mfma_f32_16x16x32_bf16(ah[m], bl, acc[m][i], 0, 0, 0);
            }
        }
    }
#pragma unroll
    for (int i = 0; i < 2; ++i) {
        const int col = (ntb + w * 2 + i) * 16 + (lane & 15);
        const float bj = bias[col];
#pragma unroll
        for (int m = 0; m < 4; ++m)
#pragma unroll
            for (int r = 0; r < 4; ++r) {
                const int row = bm + m * 16 + ((lane >> 4) << 2) + r;
                C1[(size_t)row * 512 + col] = fmaxf(acc[m][i][r] + bj, 0.f);
            }
    }
}

// ---------------------------------------------------------------------------
// Fused cell stages 2+3: XC[:,256:384] = (relu(C1@Wr2+br2)) @ Wr3 + br3.
// 512 threads, 32-row blocks. Stage1: nt = w+8i (16 tiles); stage2: nt = w.
// ---------------------------------------------------------------------------
__global__ __launch_bounds__(512) void cell_s23(
    const float* __restrict__ C1,                          // [8192][512]
    const unsigned short* __restrict__ B2h, const unsigned short* __restrict__ B2l,  // Wr2 KS=16 NT=16
    const unsigned short* __restrict__ B3h, const unsigned short* __restrict__ B3l,  // Wr3 KS=8  NT=8
    const float* __restrict__ br2, const float* __restrict__ br3,
    float* __restrict__ XC)
{
    __shared__ unsigned short Ahs[32 * 40], Als[32 * 40];
    __shared__ unsigned short Th[32 * 264], Tl[32 * 264];
    const int tid = threadIdx.x, lane = tid & 63, w = tid >> 6;
    const int bm = blockIdx.x * 32;
    const int l15 = lane & 15, g8 = (lane >> 4) << 3, g4 = (lane >> 4) << 2;
    const int l8 = lane << 3;

    // ---- stage 1: T = relu(C1 @ Wr2 + br2), K=512 (KS=16), N=256 (16 tiles)
    f32x4 acc[2][2];
#pragma unroll
    for (int m = 0; m < 2; ++m)
#pragma unroll
        for (int i = 0; i < 2; ++i) acc[m][i] = (f32x4){0.f, 0.f, 0.f, 0.f};
    for (int ks = 0; ks < 16; ++ks) {
        __syncthreads();
        if (tid < 256) {
            const int row = tid >> 3, f4 = tid & 7;
            const int k = ks * 32 + f4 * 4;                // K=512 exact
            const float4 v = *(const float4*)(C1 + (size_t)(bm + row) * 512 + k);
            unsigned h01, l01, h23, l23;
            split_pair(v.x, v.y, h01, l01);
            split_pair(v.z, v.w, h23, l23);
            *(uint2*)(Ahs + row * 40 + f4 * 4) = make_uint2(h01, h23);
            *(uint2*)(Als + row * 40 + f4 * 4) = make_uint2(l01, l23);
        }
        __syncthreads();
        bf16x8 ah[2], al[2];
#pragma unroll
        for (int m = 0; m < 2; ++m) {
            const int off = (m * 16 + l15) * 40 + g8;
            ah[m] = *(const bf16x8*)(Ahs + off);
            al[m] = *(const bf16x8*)(Als + off);
        }
#pragma unroll
        for (int i = 0; i < 2; ++i) {
            const int nt = w + 8 * i;
            const int bo_ = ((nt * 16 + ks) << 9) + l8;
            const bf16x8 bh = *(const bf16x8*)(B2h + bo_);
            const bf16x8 bl = *(const bf16x8*)(B2l + bo_);
#pragma unroll
            for (int m = 0; m < 2; ++m) {
                acc[m][i] = __builtin_amdgcn_mfma_f32_16x16x32_bf16(ah[m], bh, acc[m][i], 0, 0, 0);
                acc[m][i] = __builtin_amdgcn_mfma_f32_16x16x32_bf16(al[m], bh, acc[m][i], 0, 0, 0);
                acc[m][i] = __builtin_amdgcn_mfma_f32_16x16x32_bf16(ah[m], bl, acc[m][i], 0, 0, 0);
            }
        }
    }
#pragma unroll
    for (int i = 0; i < 2; ++i) {
        const int col = (w + 8 * i) * 16 + l15;
        const float bj = br2[col];
#pragma unroll
        for (int m = 0; m < 2; ++m)
#pragma unroll
            for (int r = 0; r < 4; ++r) {
                const int row = m * 16 + g4 + r;
                const float v = fmaxf(acc[m][i][r] + bj, 0.f);
                unsigned short h, l; split2(v, h, l);
                Th[row * 264 + col] = h;
                Tl[row * 264 + col] = l;
            }
    }
    __syncthreads();

    // ---- stage 2: XC[:,256+] = T @ Wr3 + br3, K=256 (KS=8), N=128 (8 tiles)
    f32x4 acc2[2];
    acc2[0] = (f32x4){0.f, 0.f, 0.f, 0.f};
    acc2[1] = (f32x4){0.f, 0.f, 0.f, 0.f};
#pragma unroll
    for (int ks = 0; ks < 8; ++ks) {
        bf16x8 ah[2], al[2];
#pragma unroll
        for (int m = 0; m < 2; ++m) {
            const int off = (m * 16 + l15) * 264 + ks * 32 + g8;
            ah[m] = *(const bf16x8*)(Th + off);
            al[m] = *(const bf16x8*)(Tl + off);
        }
        const int bo_ = ((w * 8 + ks) << 9) + l8;
        const bf16x8 bh = *(const bf16x8*)(B3h + bo_);
        const bf16x8 bl = *(const bf16x8*)(B3l + bo_);
#pragma unroll
        for (int m = 0; m < 2; ++m) {
            acc2[m] = __builtin_amdgcn_mfma_f32_16x16x32_bf16(ah[m], bh, acc2[m], 0, 0, 0);
            acc2[m] = __builtin_amdgcn_mfma_f32_16x16x32_bf16(al[m], bh, acc2[m], 0, 0, 0);
            acc2[m] = __builtin_amdgcn_mfma_f32_16x16x32_bf16(ah[m], bl, acc2[m], 0, 0, 0);
        }
    }
    {
        const int col = w * 16 + l15;
        const float bj = br3[col];
#pragma unroll
        for (int m = 0; m < 2; ++m)
#pragma unroll
            for (int r = 0; r < 4; ++r) {
                const int row = bm + m * 16 + g4 + r;
                XC[(size_t)row * 384 + 256 + col] = acc2[m][r] + bj;
            }
    }
}

// ---------------------------------------------------------------------------
// Fused drug heads: XC[:,0:128 / 128:256] = (relu(G@Wg1+bg1)) @ Wg2 + bg2.
// 512 threads, 64-row blocks. Stage1: nt = w+8i (<10); stage2: nt = w.
// ---------------------------------------------------------------------------
__global__ __launch_bounds__(512) void drughead(
    const float* __restrict__ G,                           // [16384][312]
    const unsigned short* __restrict__ B1h, const unsigned short* __restrict__ B1l,
    const unsigned short* __restrict__ B2h, const unsigned short* __restrict__ B2l,
    const float* __restrict__ bg1, const float* __restrict__ bg2,
    float* __restrict__ XC)
{
    __shared__ unsigned short Ahs[64 * 40], Als[64 * 40];
    __shared__ unsigned short Th[64 * 168], Tl[64 * 168];
    const int tid = threadIdx.x, lane = tid & 63, w = tid >> 6;
    const int bm = blockIdx.x * 64;
    const int l15 = lane & 15, g8 = (lane >> 4) << 3, g4 = (lane >> 4) << 2;
    const int l8 = lane << 3;

    // ---- stage 1: T = relu(G @ Wg1 + bg1), K=312 (KS=10), N=156 (10 tiles)
    f32x4 acc[4][2];
#pragma unroll
    for (int m = 0; m < 4; ++m)
#pragma unroll
        for (int i = 0; i < 2; ++i) acc[m][i] = (f32x4){0.f, 0.f, 0.f, 0.f};
    for (int ks = 0; ks < 10; ++ks) {
        __syncthreads();
        {
            const int row = tid >> 3, f4 = tid & 7;
            const int k = ks * 32 + f4 * 4;
            const float4 v = (k < 312) ? *(const float4*)(G + (size_t)(bm + row) * 312 + k)
                                       : make_float4(0.f, 0.f, 0.f, 0.f);
            unsigned h01, l01, h23, l23;
            split_pair(v.x, v.y, h01, l01);
            split_pair(v.z, v.w, h23, l23);
            *(uint2*)(Ahs + row * 40 + f4 * 4) = make_uint2(h01, h23);
            *(uint2*)(Als + row * 40 + f4 * 4) = make_uint2(l01, l23);
        }
        __syncthreads();
        bf16x8 ah[4], al[4];
#pragma unroll
        for (int m = 0; m < 4; ++m) {
            const int off = (m * 16 + l15) * 40 + g8;
            ah[m] = *(const bf16x8*)(Ahs + off);
            al[m] = *(const bf16x8*)(Als + off);
        }
#pragma unroll
        for (int i = 0; i < 2; ++i) {
            const int nt = w + 8 * i;
            if (nt < 10) {
                const int bo = ((nt * 10 + ks) << 9) + l8;
                const bf16x8 bh = *(const bf16x8*)(B1h + bo);
                const bf16x8 bl = *(const bf16x8*)(B1l + bo);
#pragma unroll
                for (int m = 0; m < 4; ++m) {
                    acc[m][i] = __builtin_amdgcn_mfma_f32_16x16x32_bf16(ah[m], bh, acc[m][i], 0, 0, 0);
                    acc[m][i] = __builtin_amdgcn_mfma_f32_16x16x32_bf16(al[m], bh, acc[m][i], 0, 0, 0);
                    acc[m][i] = __builtin_amdgcn_mfma_f32_16x16x32_bf16(ah[m], bl, acc[m][i], 0, 0, 0);
                }
            }
        }
    }
    // epi1: relu+bias, split -> T (cols 156..159 zeroed for NaN safety)
#pragma unroll
    for (int i = 0; i < 2; ++i) {
        const int nt = w + 8 * i;
        if (nt < 10) {
            const int col = nt * 16 + l15;
            const float bj = (col < 156) ? bg1[col] : 0.f;
#pragma unroll
            for (int m = 0; m < 4; ++m)
#pragma unroll
                for (int r = 0; r < 4; ++r) {
                    const int row = m * 16 + g4 + r;
                    float v = (col < 156) ? fmaxf(acc[m][i][r] + bj, 0.f) : 0.f;
                    unsigned short h, l; split2(v, h, l);
                    Th[row * 168 + col] = h;
                    Tl[row * 168 + col] = l;
                }
        }
    }
    __syncthreads();

    // ---- stage 2: XC cols = T @ Wg2 + bg2, K=156 (KS=5), N=128 (8 tiles)
    f32x4 acc2[4];
#pragma unroll
    for (int m = 0; m < 4; ++m) acc2[m] = (f32x4){0.f, 0.f, 0.f, 0.f};
#pragma unroll
    for (int ks = 0; ks < 5; ++ks) {
        bf16x8 ah[4], al[4];
#pragma unroll
        for (int m = 0; m < 4; ++m) {
            const int off = (m * 16 + l15) * 168 + ks * 32 + g8;
            ah[m] = *(const bf16x8*)(Th + off);
            al[m] = *(const bf16x8*)(Tl + off);
        }
        const int bo = ((w * 5 + ks) << 9) + l8;
        const bf16x8 bh = *(const bf16x8*)(B2h + bo);
        const bf16x8 bl = *(const bf16x8*)(B2l + bo);
#pragma unroll
        for (int m = 0; m < 4; ++m) {
            acc2[m] = __builtin_amdgcn_mfma_f32_16x16x32_bf16(ah[m], bh, acc2[m], 0, 0, 0);
            acc2[m] = __builtin_amdgcn_mfma_f32_16x16x32_bf16(al[m], bh, acc2[m], 0, 0, 0);
            acc2[m] = __builtin_amdgcn_mfma_f32_16x16x32_bf16(ah[m], bl, acc2[m], 0, 0, 0);
        }
    }
    {
        const int col = w * 16 + l15;
        const float bj = bg2[col];
#pragma unroll
        for (int m = 0; m < 4; ++m)
#pragma unroll
            for (int r = 0; r < 4; ++r) {
                const int row = bm + m * 16 + g4 + r;
                const int crow = row & (BGRAPH - 1);
                const int cadd = (row >> 13) * 128;
                XC[(size_t)crow * 384 + cadd + col] = acc2[m][r] + bj;
            }
    }
}

// ---------------------------------------------------------------------------
// Fused head: out = (relu(relu(XC@Wf1+bf1)@Wf2+bf2)) @ Wo + bo.
// 512 threads, 32-row blocks. Stage1: nt = w+8i; stage2: nt = w; stage3 w==0.
// ---------------------------------------------------------------------------
__global__ __launch_bounds__(512) void head_fused(
    const float* __restrict__ XC,                          // [8192][384]
    const unsigned short* __restrict__ B1h, const unsigned short* __restrict__ B1l,
    const unsigned short* __restrict__ B2h, const unsigned short* __restrict__ B2l,
    const unsigned short* __restrict__ B3h, const unsigned short* __restrict__ B3l,
    const float* __restrict__ bf1, const float* __restrict__ bf2, const float* __restrict__ bo,
    float* __restrict__ out)
{
    __shared__ unsigned short Ahs[32 * 40], Als[32 * 40];
    __shared__ unsigned short T1h[32 * 280], T1l[32 * 280];
    unsigned short* T2h = T1h;                             // aliased, stride 136
    unsigned short* T2l = T1l;
    const int tid = threadIdx.x, lane = tid & 63, w = tid >> 6;
    const int bm = blockIdx.x * 32;
    const int l15 = lane & 15, g8 = (lane >> 4) << 3, g4 = (lane >> 4) << 2;
    const int l8 = lane << 3;

    // ---- stage 1: T1 = relu(XC @ Wf1 + bf1), K=384 (KS=12), N=256 (16 tiles)
    f32x4 acc[2][2];
#pragma unroll
    for (int m = 0; m < 2; ++m)
#pragma unroll
        for (int i = 0; i < 2; ++i) acc[m][i] = (f32x4){0.f, 0.f, 0.f, 0.f};
    for (int ks = 0; ks < 12; ++ks) {
        __syncthreads();
        if (tid < 256) {
            const int row = tid >> 3, f4 = tid & 7;
            const int k = ks * 32 + f4 * 4;                // K=384 exact
            const float4 v = *(const float4*)(XC + (size_t)(bm + row) * 384 + k);
            unsigned h01, l01, h23, l23;
            split_pair(v.x, v.y, h01, l01);
            split_pair(v.z, v.w, h23, l23);
            *(uint2*)(Ahs + row * 40 + f4 * 4) = make_uint2(h01, h23);
            *(uint2*)(Als + row * 40 + f4 * 4) = make_uint2(l01, l23);
        }
        __syncthreads();
        bf16x8 ah[2], al[2];
#pragma unroll
        for (int m = 0; m < 2; ++m) {
            const int off = (m * 16 + l15) * 40 + g8;
            ah[m] = *(const bf16x8*)(Ahs + off);
            al[m] = *(const bf16x8*)(Als + off);
        }
#pragma unroll
        for (int i = 0; i < 2; ++i) {
            const int nt = w + 8 * i;
            const int bo_ = ((nt * 12 + ks) << 9) + l8;
            const bf16x8 bh = *(const bf16x8*)(B1h + bo_);
            const bf16x8 bl = *(const bf16x8*)(B1l + bo_);
#pragma unroll
            for (int m = 0; m < 2; ++m) {
                acc[m][i] = __builtin_amdgcn_mfma_f32_16x16x32_bf16(ah[m], bh, acc[m][i], 0, 0, 0);
                acc[m][i] = __builtin_amdgcn_mfma_f32_16x16x32_bf16(al[m], bh, acc[m][i], 0, 0, 0);
                acc[m][i] = __builtin_amdgcn_mfma_f32_16x16x32_bf16(ah[m], bl, acc[m][i], 0, 0, 0);
            }
        }
    }
#pragma unroll
    for (int i = 0; i < 2; ++i) {
        const int col = (w + 8 * i) * 16 + l15;
        const float bj = bf1[col];
#pragma unroll
        for (int m = 0; m < 2; ++m)
#pragma unroll
            for (int r = 0; r < 4; ++r) {
                const int row = m * 16 + g4 + r;
                const float v = fmaxf(acc[m][i][r] + bj, 0.f);
                unsigned short h, l; split2(v, h, l);
                T1h[row * 280 + col] = h;
                T1l[row * 280 + col] = l;
            }
    }
    __syncthreads();

    // ---- stage 2: T2 = relu(T1 @ Wf2 + bf2), K=256 (KS=8), N=128 (8 tiles)
    f32x4 acc2[2];
    acc2[0] = (f32x4){0.f, 0.f, 0.f, 0.f};
    acc2[1] = (f32x4){0.f, 0.f, 0.f, 0.f};
#pragma unroll
    for (int ks = 0; ks < 8; ++ks) {
        bf16x8 ah[2], al[2];
#pragma unroll
        for (int m = 0; m < 2; ++m) {
            const int off = (m * 16 + l15) * 280 + ks * 32 + g8;
            ah[m] = *(const bf16x8*)(T1h + off);
            al[m] = *(const bf16x8*)(T1l + off);
        }
        const int bo_ = ((w * 8 + ks) << 9) + l8;
        const bf16x8 bh = *(const bf16x8*)(B2h + bo_);
        const bf16x8 bl = *(const bf16x8*)(B2l + bo_);
#pragma unroll
        for (int m = 0; m < 2; ++m) {
            acc2[m] = __builtin_amdgcn_mfma_f32_16x16x32_bf16(ah[m], bh, acc2[m], 0, 0, 0);
            acc2[m] = __builtin_amdgcn_mfma_f32_16x16x32_bf16(al[m], bh, acc2[m], 0, 0, 0);
            acc2[m] = __builtin_amdgcn_mfma_f32_16x16x32_bf16(ah[m], bl, acc2[m], 0, 0, 0);
        }
    }
    __syncthreads();                       // all T1 reads done (T2 aliases T1)
    {
        const int col = w * 16 + l15;
        const float bj = bf2[col];
#pragma unroll
        for (int m = 0; m < 2; ++m)
#pragma unroll
            for (int r = 0; r < 4; ++r) {
                const int row = m * 16 + g4 + r;
                const float v = fmaxf(acc2[m][r] + bj, 0.f);
                unsigned short h, l; split2(v, h, l);
                T2h[row * 136 + col] = h;
                T2l[row * 136 + col] = l;
            }
    }
    __syncthreads();

    // ---- stage 3: out = T2 @ Wo + bo, K=128 (KS=4), N=2 (tile 0, wave 0)
    if (w == 0) {
        f32x4 acc3[2];
        acc3[0] = (f32x4){0.f, 0.f, 0.f, 0.f};
        acc3[1] = (f32x4){0.f, 0.f, 0.f, 0.f};
#pragma unroll
        for (int ks = 0; ks < 4; ++ks) {
            bf16x8 ah[2], al[2];
#pragma unroll
            for (int m = 0; m < 2; ++m) {
                const int off = (m * 16 + l15) * 136 + ks * 32 + g8;
                ah[m] = *(const bf16x8*)(T2h + off);
                al[m] = *(const bf16x8*)(T2l + off);
            }
            const int bo_ = (ks << 9) + l8;
            const bf16x8 bh = *(const bf16x8*)(B3h + bo_);
            const bf16x8 bl = *(const bf16x8*)(B3l + bo_);
#pragma unroll
            for (int m = 0; m < 2; ++m) {
                acc3[m] = __builtin_amdgcn_mfma_f32_16x16x32_bf16(ah[m], bh, acc3[m], 0, 0, 0);
                acc3[m] = __builtin_amdgcn_mfma_f32_16x16x32_bf16(al[m], bh, acc3[m], 0, 0, 0);
                acc3[m] = __builtin_amdgcn_mfma_f32_16x16x32_bf16(ah[m], bl, acc3[m], 0, 0, 0);
            }
        }
        if (l15 < 2) {
            const float bj = bo[l15];
#pragma unroll
            for (int m = 0; m < 2; ++m)
#pragma unroll
                for (int r = 0; r < 4; ++r)
                    out[(size_t)(bm + m * 16 + g4 + r) * 2 + l15] = acc3[m][r] + bj;
        }
    }
}

// ---------------------------------------------------------------------------

extern "C" void kernel_launch(void* const* d_in, const int* in_sizes, int n_in,
                              void* d_out, int out_size, void* d_ws, size_t ws_size,
                              hipStream_t stream)
{
    (void)in_sizes; (void)n_in; (void)out_size; (void)ws_size;
    const float* x1   = (const float*)d_in[0];
    const int*   ei1  = (const int*)d_in[1];
    const float* x2   = (const float*)d_in[3];
    const int*   ei2  = (const int*)d_in[4];
    const float* cell = (const float*)d_in[6];
    const float* Wc1 = (const float*)d_in[7],  *bc1 = (const float*)d_in[8];
    const float* Wc2 = (const float*)d_in[9],  *bc2 = (const float*)d_in[10];
    const float* Wc3 = (const float*)d_in[11], *bc3 = (const float*)d_in[12];
    const float* Wg1 = (const float*)d_in[13], *bg1 = (const float*)d_in[14];
    const float* Wg2 = (const float*)d_in[15], *bg2 = (const float*)d_in[16];
    const float* Wr1 = (const float*)d_in[17], *br1 = (const float*)d_in[18];
    const float* Wr2 = (const float*)d_in[19], *br2 = (const float*)d_in[20];
    const float* Wr3 = (const float*)d_in[21], *br3 = (const float*)d_in[22];
    const float* Wf1 = (const float*)d_in[23], *bf1 = (const float*)d_in[24];
    const float* Wf2 = (const float*)d_in[25], *bf2 = (const float*)d_in[26];
    const float* Wo  = (const float*)d_in[27], *bo  = (const float*)d_in[28];
    float* out = (float*)d_out;
    float* ws  = (float*)d_ws;

    size_t o = 0;
    auto allocF = [&](size_t n) { float* p = ws + o; o += n; return p; };
    auto allocU = [&](size_t n) { unsigned short* p = (unsigned short*)(ws + o); o += n / 2; return p; };

    float* G1  = allocF((size_t)2 * BGRAPH * 312);   // both branches stacked
    float* C1  = allocF((size_t)BGRAPH * 512);
    float* XC  = allocF((size_t)BGRAPH * 384);

    // swizzled split weights (ushort counts = NT*KS*512)
    const int sWc1 = 8  * 3  * 512, sWc2 = 12 * 3  * 512, sWc3 = 20 * 5  * 512;
    const int sWg1 = 10 * 10 * 512, sWg2 = 8  * 5  * 512;
    const int sWr1 = 32 * 30 * 512, sWr2 = 16 * 16 * 512, sWr3 = 8 * 8 * 512;
    const int sWf1 = 16 * 12 * 512, sWf2 = 8  * 8  * 512, sWoo = 1 * 4 * 512;
    unsigned short *Wc1h = allocU(sWc1), *Wc1l = allocU(sWc1);
    unsigned short *Wc2h = allocU(sWc2), *Wc2l = allocU(sWc2);
    unsigned short *Wc3h = allocU(sWc3), *Wc3l = allocU(sWc3);
    unsigned short *Wg1h = allocU(sWg1), *Wg1l = allocU(sWg1);
    unsigned short *Wg2h = allocU(sWg2), *Wg2l = allocU(sWg2);
    unsigned short *Wr1h = allocU(sWr1), *Wr1l = allocU(sWr1);
    unsigned short *Wr2h = allocU(sWr2), *Wr2l = allocU(sWr2);
    unsigned short *Wr3h = allocU(sWr3), *Wr3l = allocU(sWr3);
    unsigned short *Wf1h = allocU(sWf1), *Wf1l = allocU(sWf1);
    unsigned short *Wf2h = allocU(sWf2), *Wf2l = allocU(sWf2);
    unsigned short *Wooh = allocU(sWoo), *Wool = allocU(sWoo);

    // one fused weight-prep launch
    WTab tab;
    int base = 0, ti = 0;
    auto addw = [&](const float* W, int K, int N, int KS, int NT,
                    unsigned short* Bh, unsigned short* Bl) {
        tab.d[ti] = WDesc{W, Bh, Bl, K, N, KS, NT, base};
        base += NT * KS * 2;              // blocks = NT*KS*512/256
        ++ti;
    };
    addw(Wc1, 78, 78, 3, 8, Wc1h, Wc1l);
    addw(Wc2, 78, 156, 3, 12, Wc2h, Wc2l);
    addw(Wc3, 156, 312, 5, 20, Wc3h, Wc3l);
    addw(Wg1, 312, 156, 10, 10, Wg1h, Wg1l);
    addw(Wg2, 156, 128, 5, 8, Wg2h, Wg2l);
    addw(Wr1, 954, 512, 30, 32, Wr1h, Wr1l);
    addw(Wr2, 512, 256, 16, 16, Wr2h, Wr2l);
    addw(Wr3, 256, 128, 8, 8, Wr3h, Wr3l);
    addw(Wf1, 384, 256, 12, 16, Wf1h, Wf1l);
    addw(Wf2, 256, 128, 8, 8, Wf2h, Wf2l);
    addw(Wo,  128, 2,   4, 1, Wooh, Wool);
    wprep_all<<<base, 256, 0, stream>>>(tab);

    // both drug branches (GCN x3 + maxpool) in one launch; G2 follows G1
    gcn_graph<<<2 * BGRAPH, GT, 0, stream>>>(x1, ei1, x2, ei2,
        Wc1h, Wc1l, Wc2h, Wc2l, Wc3h, Wc3l, bc1, bc2, bc3, G1);

    // fused drug heads (M = 16384): G -> XC[:,0:128] / [:,128:256]
    drughead<<<256, 512, 0, stream>>>(G1, Wg1h, Wg1l, Wg2h, Wg2l, bg1, bg2, XC);

    // cell MLP -> XC[:,256:384] (stage 1 fuses the L2 normalize; 2+3 fused)
    cell_s1<<<dim3(128, 2), 512, 0, stream>>>(cell, Wr1h, Wr1l, br1, C1);
    cell_s23<<<256, 512, 0, stream>>>(C1, Wr2h, Wr2l, Wr3h, Wr3l, br2, br3, XC);

    // fused head: XC -> out
    head_fused<<<256, 512, 0, stream>>>(XC, Wf1h, Wf1l, Wf2h, Wf2l, Wooh, Wool,
                                        bf1, bf2, bo, out);
}

// Round 13
// 734.715 us; speedup vs baseline: 1.5923x; 1.0129x over previous
//
#include <hip/hip_runtime.h>
#include <math.h>

#define EE 819200          // edges total
#define BGRAPH 8192        // graphs
constexpr int GT = 512;    // threads, graph kernel (8 waves)

typedef __attribute__((ext_vector_type(8))) short bf16x8;   // 4 VGPRs = 8 bf16
typedef __attribute__((ext_vector_type(4))) float f32x4;

// ---- fp32 -> bf16 split (RNE), a ~= hi + lo, |a-(hi+lo)| <= 2^-18 |a| ----
__device__ inline unsigned short f2bf(float x) {
    unsigned u = __float_as_uint(x);
    u += 0x7fffu + ((u >> 16) & 1u);
    return (unsigned short)(u >> 16);
}
__device__ inline float bf2f(unsigned short h) {
    return __uint_as_float(((unsigned)h) << 16);
}
__device__ inline void split2(float v, unsigned short& hi, unsigned short& lo) {
    hi = f2bf(v);
    lo = f2bf(v - bf2f(hi));
}
// packed RNE split of a value-pair: h = {bf16(b)|bf16(a)}, l = residuals
__device__ inline unsigned cvtpk_bf16(float a, float b) {
    unsigned r;
    asm("v_cvt_pk_bf16_f32 %0, %1, %2" : "=v"(r) : "v"(a), "v"(b));
    return r;
}
__device__ inline void split_pair(float a, float b, unsigned& h, unsigned& l) {
    h = cvtpk_bf16(a, b);
    const float ra = a - __uint_as_float(h << 16);
    const float rb = b - __uint_as_float(h & 0xffff0000u);
    l = cvtpk_bf16(ra, rb);
}

// ---------------------------------------------------------------------------
// Fused weight prep (one launch): W[K][N] fp32 -> fragment-ordered hi/lo bf16,
// zero-padded to (KS*32) x (NT*16).
// ---------------------------------------------------------------------------
struct WDesc { const float* W; unsigned short* Bh; unsigned short* Bl;
               int K, N, KS, NT, base; };
struct WTab { WDesc d[11]; };

__global__ __launch_bounds__(256) void wprep_all(WTab tab)
{
    const int bid = blockIdx.x;
    int t = 0;
#pragma unroll
    for (int i = 1; i < 11; ++i) if (bid >= tab.d[i].base) t = i;
    const WDesc D = tab.d[t];
    const int idx = (bid - D.base) * 256 + (int)threadIdx.x;
    if (idx >= D.NT * D.KS * 512) return;
    const int r    = idx & 7;
    const int lane = (idx >> 3) & 63;
    const int rest = idx >> 9;
    const int ks   = rest % D.KS;
    const int nt   = rest / D.KS;
    const int k = ks * 32 + ((lane >> 4) << 3) + r;
    const int n = nt * 16 + (lane & 15);
    const float v = (k < D.K && n < D.N) ? D.W[(size_t)k * D.N + n] : 0.f;
    unsigned short h, l; split2(v, h, l);
    D.Bh[idx] = h; D.Bl[idx] = l;
}

// ---------------------------------------------------------------------------
// Per-graph fused 3-layer GCN + max pool, bf16x3 MFMA (R9/R11 structure).
// act fp32 [50][164] (odd float4 stride). Frags [50][168] hi/lo.
// ---------------------------------------------------------------------------

template<int KS, int NI, int FOUT>   // K-steps; n-tiles/wave; real out cols
__device__ inline void layer_run(const unsigned short* __restrict__ Bh,
                                 const unsigned short* __restrict__ Bl,
                                 const unsigned short* Ah, const unsigned short* Al,
                                 f32x4 (&acc)[2][5], int mg, int ng, int lane)
{
#pragma unroll
    for (int m = 0; m < 2; ++m)
#pragma unroll
        for (int i = 0; i < NI; ++i) acc[m][i] = (f32x4){0.f, 0.f, 0.f, 0.f};
    const int g8 = (lane >> 4) << 3;
    const int l8 = lane << 3;
#pragma unroll
    for (int ks = 0; ks < KS; ++ks) {
        bf16x8 ah[2], al[2];
#pragma unroll
        for (int m = 0; m < 2; ++m) {
            const int off = (mg * 32 + m * 16 + (lane & 15)) * 168 + ks * 32 + g8;
            ah[m] = *(const bf16x8*)(Ah + off);
            al[m] = *(const bf16x8*)(Al + off);
        }
#pragma unroll
        for (int i = 0; i < NI; ++i) {
            const int nt = ng + (i << 2);
            if (nt * 16 < FOUT) {              // skip all-zero W tiles (uniform)
                const int bo = ((nt * KS + ks) << 9) + l8;
                const bf16x8 bh = *(const bf16x8*)(Bh + bo);
                const bf16x8 bl = *(const bf16x8*)(Bl + bo);
#pragma unroll
                for (int m = 0; m < 2; ++m) {
                    acc[m][i] = __builtin_amdgcn_mfma_f32_16x16x32_bf16(ah[m], bh, acc[m][i], 0, 0, 0);
                    acc[m][i] = __builtin_amdgcn_mfma_f32_16x16x32_bf16(al[m], bh, acc[m][i], 0, 0, 0);
                    acc[m][i] = __builtin_amdgcn_mfma_f32_16x16x32_bf16(ah[m], bl, acc[m][i], 0, 0, 0);
                }
            }
        }
    }
}

// D layout: col = lane&15 (+16*nt), row = (lane>>4)*4 + reg (+16*mt)
template<int NI, int NCOL>
__device__ inline void epi_store(const f32x4 (&acc)[2][5], const float* __restrict__ bias,
                                 float* act, int mg, int ng, int lane)
{
#pragma unroll
    for (int i = 0; i < NI; ++i) {
        const int col = (ng + (i << 2)) * 16 + (lane & 15);
        if (col < NCOL) {
            const float bj = bias[col];
#pragma unroll
            for (int m = 0; m < 2; ++m)
#pragma unroll
                for (int r = 0; r < 4; ++r) {
                    const int row = mg * 32 + m * 16 + ((lane >> 4) << 2) + r;
                    if (row < 50)
                        act[row * 164 + col] = fmaxf(acc[m][i][r] + bj, 0.f);
                }
        }
    }
}

__device__ inline void pool_store(const f32x4 (&acc)[2][5], const float* __restrict__ bias,
                                  unsigned* gmax, int mg, int ng, int lane)
{
#pragma unroll
    for (int i = 0; i < 5; ++i) {
        const int col = (ng + (i << 2)) * 16 + (lane & 15);
        const float bj = (col < 312) ? bias[col] : 0.f;
        float m = 0.f;                      // relu floor == pool identity
#pragma unroll
        for (int mm = 0; mm < 2; ++mm)
#pragma unroll
            for (int r = 0; r < 4; ++r) {
                const int row = mg * 32 + mm * 16 + ((lane >> 4) << 2) + r;
                if (row < 50) m = fmaxf(m, acc[mm][i][r] + bj);
            }
        m = fmaxf(m, __shfl_xor(m, 16, 64));
        m = fmaxf(m, __shfl_xor(m, 32, 64));
        if (lane < 16 && col < 312)
            atomicMax(&gmax[col], __float_as_uint(m));
    }
}

// agg (Â·H) fused with bf16-split, 8 features/item (two float4 chains),
// edge-pair unrolling, cvt_pk RNE splits, b128 stores. act4 stride 41 (odd).
template<int NCOL>
__device__ inline void agg_split8(const float4* __restrict__ act4,
                                  unsigned short* Ah, unsigned short* Al,
                                  const int* insrc, const float* insn,
                                  const int* inoff, const float* selfw, int tid)
{
    constexpr int CH = (NCOL + 7) / 8;     // 8-float chunks per row (pads zero)
    for (int idx = tid; idx < 50 * CH; idx += GT) {
        const int n = idx / CH;            // constexpr divisor -> magic-mul
        const int c2 = (idx - n * CH) * 2; // float4 index within row
        const float sw = selfw[n];
        const float4 v0 = act4[n * 41 + c2];
        const float4 v1 = act4[n * 41 + c2 + 1];
        float4 a0, a1;
        a0.x = sw * v0.x; a0.y = sw * v0.y; a0.z = sw * v0.z; a0.w = sw * v0.w;
        a1.x = sw * v1.x; a1.y = sw * v1.y; a1.z = sw * v1.z; a1.w = sw * v1.w;
        int j = inoff[n];
        const int j1 = inoff[n + 1];
        for (; j + 1 < j1; j += 2) {
            const int s0 = insrc[j] * 41 + c2;
            const int s1 = insrc[j + 1] * 41 + c2;
            const float w0 = insn[j], w1 = insn[j + 1];
            const float4 e00 = act4[s0], e01 = act4[s0 + 1];
            const float4 e10 = act4[s1], e11 = act4[s1 + 1];
            a0.x = fmaf(w1, e10.x, fmaf(w0, e00.x, a0.x));
            a0.y = fmaf(w1, e10.y, fmaf(w0, e00.y, a0.y));
            a0.z = fmaf(w1, e10.z, fmaf(w0, e00.z, a0.z));
            a0.w = fmaf(w1, e10.w, fmaf(w0, e00.w, a0.w));
            a1.x = fmaf(w1, e11.x, fmaf(w0, e01.x, a1.x));
            a1.y = fmaf(w1, e11.y, fmaf(w0, e01.y, a1.y));
            a1.z = fmaf(w1, e11.z, fmaf(w0, e01.z, a1.z));
            a1.w = fmaf(w1, e11.w, fmaf(w0, e01.w, a1.w));
        }
        if (j < j1) {
            const int s0 = insrc[j] * 41 + c2;
            const float w0 = insn[j];
            const float4 e00 = act4[s0], e01 = act4[s0 + 1];
            a0.x = fmaf(w0, e00.x, a0.x);
            a0.y = fmaf(w0, e00.y, a0.y);
            a0.z = fmaf(w0, e00.z, a0.z);
            a0.w = fmaf(w0, e00.w, a0.w);
            a1.x = fmaf(w0, e01.x, a1.x);
            a1.y = fmaf(w0, e01.y, a1.y);
            a1.z = fmaf(w0, e01.z, a1.z);
            a1.w = fmaf(w0, e01.w, a1.w);
        }
        unsigned h01, h23, h45, h67, l01, l23, l45, l67;
        split_pair(a0.x, a0.y, h01, l01);
        split_pair(a0.z, a0.w, h23, l23);
        split_pair(a1.x, a1.y, h45, l45);
        split_pair(a1.z, a1.w, h67, l67);
        const int off = n * 168 + (c2 << 2);           // 16B-aligned
        *(uint4*)(Ah + off) = make_uint4(h01, h23, h45, h67);
        *(uint4*)(Al + off) = make_uint4(l01, l23, l45, l67);
    }
}

__global__ __launch_bounds__(GT, 4) void gcn_graph(
    const float* __restrict__ x1, const int* __restrict__ ei1,
    const float* __restrict__ x2, const int* __restrict__ ei2,
    const unsigned short* __restrict__ W1h, const unsigned short* __restrict__ W1l,
    const unsigned short* __restrict__ W2h, const unsigned short* __restrict__ W2l,
    const unsigned short* __restrict__ W3h, const unsigned short* __restrict__ W3l,
    const float* __restrict__ bc1, const float* __restrict__ bc2, const float* __restrict__ bc3,
    float* __restrict__ G)              // [2*B,312]
{
    __shared__ __align__(16) unsigned short Ah[50 * 168], Al[50 * 168];
    __shared__ float4 act4s[50 * 41];                       // fp32 act [50][164]
    __shared__ int   es[100], ed[100], insrc[100];
    __shared__ float insn[100];
    __shared__ int   inoff[51], cnt[50], cnt2[50];
    __shared__ float dinvs[50], selfw[50];
    __shared__ unsigned gmax[312];

    const int br = blockIdx.x >> 13;
    const int b  = blockIdx.x & (BGRAPH - 1);
    const float* X    = br ? x2 : x1;
    const int*   srcA = br ? ei2 : ei1;
    const int*   dstA = srcA + EE;
    const int nb = b * 50, eb = b * 100, tid = threadIdx.x;
    const int lane = tid & 63;
    const int w = tid >> 6;
    const int mg = w >> 2, ng = w & 3;
    float* act = (float*)act4s;
    const float4* act4 = act4s;

    // ---- P1: X -> LDS directly (cols 0..77; disjoint from zero bands),
    //          zero only what must be zero, load edges
    for (int idx = tid; idx < 3900; idx += GT) {            // fully coalesced
        const int n = idx / 78, c = idx - n * 78;
        act[n * 164 + c] = X[(size_t)nb * 78 + idx];
    }
    // act zero bands: cols 78,79 (L1/L2 agg tail) + 156..159 (L3 agg tail)
    for (int i = tid; i < 300; i += GT) {
        const int n = i / 6, j = i - 6 * n;
        act[n * 164 + (j < 2 ? 78 + j : 154 + j)] = 0.f;
    }
    // frag k-band cols 80..95 rows 0..49 (NaN safety: L1/L2 write cols<80,
    // ks=2 reads k 64..95; W zero-pad nullifies VALUE but not NaN garbage)
    for (int i = tid; i < 50 * 8; i += GT) {
        const int n = i >> 3, c = ((i & 7) << 1) + 80;
        *(unsigned*)(Ah + n * 168 + c) = 0u;
        *(unsigned*)(Al + n * 168 + c) = 0u;
    }
    for (int i = tid; i < 312; i += GT) gmax[i] = 0u;
    for (int i = tid; i < 50; i += GT) { cnt[i] = 0; cnt2[i] = 0; }
    for (int e = tid; e < 100; e += GT) { es[e] = srcA[eb + e] - nb; ed[e] = dstA[eb + e] - nb; }
    __syncthreads();
    // ---- P2: degree count
    for (int e = tid; e < 100; e += GT) atomicAdd(&cnt[ed[e]], 1);
    __syncthreads();
    // ---- P3: dinv/selfw (parallel) + wave-parallel prefix scan (wave 0)
    for (int n = tid; n < 50; n += GT) {
        const float dv = 1.0f / sqrtf((float)cnt[n] + 1.0f);
        dinvs[n] = dv; selfw[n] = dv * dv;
    }
    if (w == 0) {                        // inclusive shfl_up scan, 6 steps
        int v = (lane < 50) ? cnt[lane] : 0;
#pragma unroll
        for (int s = 1; s < 64; s <<= 1) {
            const int t = __shfl_up(v, s, 64);
            if (lane >= s) v += t;
        }
        if (lane < 50) inoff[lane + 1] = v;
        if (lane == 0) inoff[0] = 0;
    }
    __syncthreads();
    // ---- P4: counting sort (cnt2)
    for (int e = tid; e < 100; e += GT) {
        const int d = ed[e];
        const int p = inoff[d] + atomicAdd(&cnt2[d], 1);
        insrc[p] = es[e];
        insn[p]  = dinvs[es[e]] * dinvs[d];
    }
    __syncthreads();

    f32x4 acc[2][5];

    // layer 1: agg(X) -> 78x78
    agg_split8<78>(act4, Ah, Al, insrc, insn, inoff, selfw, tid);
    __syncthreads();
    __builtin_amdgcn_s_setprio(1);
    layer_run<3, 2, 78>(W1h, W1l, Ah, Al, acc, mg, ng, lane);
    __builtin_amdgcn_s_setprio(0);
    epi_store<2, 78>(acc, bc1, act, mg, ng, lane);
    __syncthreads();

    // layer 2: agg -> 78x156
    agg_split8<78>(act4, Ah, Al, insrc, insn, inoff, selfw, tid);
    __syncthreads();
    __builtin_amdgcn_s_setprio(1);
    layer_run<3, 3, 156>(W2h, W2l, Ah, Al, acc, mg, ng, lane);
    __builtin_amdgcn_s_setprio(0);
    epi_store<3, 156>(acc, bc2, act, mg, ng, lane);
    __syncthreads();

    // layer 3: agg -> 156x312 + fused bias/relu/maxpool
    agg_split8<156>(act4, Ah, Al, insrc, insn, inoff, selfw, tid);
    __syncthreads();
    __builtin_amdgcn_s_setprio(1);
    layer_run<5, 5, 312>(W3h, W3l, Ah, Al, acc, mg, ng, lane);
    __builtin_amdgcn_s_setprio(0);
    pool_store(acc, bc3, gmax, mg, ng, lane);
    __syncthreads();
    for (int f = tid; f < 312; f += GT)
        G[(size_t)(br * BGRAPH + b) * 312 + f] = __uint_as_float(gmax[f]);
}

// ---------------------------------------------------------------------------
// Cell stage 1 with fused L2-normalize: C1 = relu(norm(cell) @ Wr1 + br1).
// 512 threads (8 waves, 2/SIMD): wave w owns n-tiles ntb + 2w + i.
// ---------------------------------------------------------------------------
__global__ __launch_bounds__(512) void cell_s1(
    const float* __restrict__ cell,                       // [8192][954]
    const unsigned short* __restrict__ Bh, const unsigned short* __restrict__ Bl,
    const float* __restrict__ bias, float* __restrict__ C1)
{
    __shared__ unsigned short Ahs[64 * 40], Als[64 * 40];
    __shared__ float rn[64];
    const int tid = threadIdx.x, lane = tid & 63, w = tid >> 6;
    const int bm = blockIdx.x * 64;
    const int ntb = blockIdx.y * 16;
    const int g8 = (lane >> 4) << 3;
    const int l8 = lane << 3;

    if (tid < 64) rn[tid] = 0.f;
    __syncthreads();
    {
        const int row = tid & 63, part = tid >> 6;        // 8 partials/row
        float ss = 0.f;
        for (int c = part; c < 954; c += 8) {
            const float v = cell[(size_t)(bm + row) * 954 + c];
            ss = fmaf(v, v, ss);
        }
        atomicAdd(&rn[row], ss);
    }
    __syncthreads();
    if (tid < 64) rn[tid] = 1.0f / fmaxf(sqrtf(rn[tid]), 1e-12f);

    f32x4 acc[4][2];
#pragma unroll
    for (int m = 0; m < 4; ++m)
#pragma unroll
        for (int i = 0; i < 2; ++i) acc[m][i] = (f32x4){0.f, 0.f, 0.f, 0.f};

    for (int ks = 0; ks < 30; ++ks) {
        __syncthreads();
        for (int idx = tid; idx < 1024; idx += 512) {
            const int row = idx >> 4, p = idx & 15;
            const int k = ks * 32 + p * 2;
            float2 v = (k < 954) ? *(const float2*)(cell + (size_t)(bm + row) * 954 + k)
                                 : make_float2(0.f, 0.f);
            const float rr = rn[row];
            unsigned h, l; split_pair(v.x * rr, v.y * rr, h, l);
            *(unsigned*)(Ahs + row * 40 + p * 2) = h;
            *(unsigned*)(Als + row * 40 + p * 2) = l;
        }
        __syncthreads();
        bf16x8 ah[4], al[4];
#pragma unroll
        for (int m = 0; m < 4; ++m) {
            const int off = (m * 16 + (lane & 15)) * 40 + g8;
            ah[m] = *(const bf16x8*)(Ahs + off);
            al[m] = *(const bf16x8*)(Als + off);
        }
#pragma unroll
        for (int i = 0; i < 2; ++i) {
            const int nt = ntb + w * 2 + i;
            const int bo = ((nt * 30 + ks) << 9) + l8;
            const bf16x8 bh = *(const bf16x8*)(Bh + bo);
            const bf16x8 bl = *(const bf16x8*)(Bl + bo);
#pragma unroll
            for (int m = 0; m < 4; ++m) {
                acc[m][i] = __builtin_amdgcn_mfma_f32_16x16x32_bf16(ah[m], bh, acc[m][i], 0, 0, 0);
                acc[m][i] = __builtin_amdgcn_mfma_f32_16x16x32_bf16(al[m], bh, acc[m][i], 0, 0, 0);
                acc[m][i] = __builtin_amdgcn_mfma_f32_16x16x32_bf16(ah[m], bl, acc[m][i], 0, 0, 0);
            }
        }
    }
#pragma unroll
    for (int i = 0; i < 2; ++i) {
        const int col = (ntb + w * 2 + i) * 16 + (lane & 15);
        const float bj = bias[col];
#pragma unroll
        for (int m = 0; m < 4; ++m)
#pragma unroll
            for (int r = 0; r < 4; ++r) {
                const int row = bm + m * 16 + ((lane >> 4) << 2) + r;
                C1[(size_t)row * 512 + col] = fmaxf(acc[m][i][r] + bj, 0.f);
            }
    }
}

// ---------------------------------------------------------------------------
// Fused cell stages 2+3: XC[:,256:384] = (relu(C1@Wr2+br2)) @ Wr3 + br3.
// 512 threads, 32-row blocks. Stage1: nt = w+8i (16 tiles); stage2: nt = w.
// ---------------------------------------------------------------------------
__global__ __launch_bounds__(512) void cell_s23(
    const float* __restrict__ C1,                          // [8192][512]
    const unsigned short* __restrict__ B2h, const unsigned short* __restrict__ B2l,  // Wr2 KS=16 NT=16
    const unsigned short* __restrict__ B3h, const unsigned short* __restrict__ B3l,  // Wr3 KS=8  NT=8
    const float* __restrict__ br2, const float* __restrict__ br3,
    float* __restrict__ XC)
{
    __shared__ unsigned short Ahs[32 * 40], Als[32 * 40];
    __shared__ unsigned short Th[32 * 264], Tl[32 * 264];
    const int tid = threadIdx.x, lane = tid & 63, w = tid >> 6;
    const int bm = blockIdx.x * 32;
    const int l15 = lane & 15, g8 = (lane >> 4) << 3, g4 = (lane >> 4) << 2;
    const int l8 = lane << 3;

    // ---- stage 1: T = relu(C1 @ Wr2 + br2), K=512 (KS=16), N=256 (16 tiles)
    f32x4 acc[2][2];
#pragma unroll
    for (int m = 0; m < 2; ++m)
#pragma unroll
        for (int i = 0; i < 2; ++i) acc[m][i] = (f32x4){0.f, 0.f, 0.f, 0.f};
    for (int ks = 0; ks < 16; ++ks) {
        __syncthreads();
        if (tid < 256) {
            const int row = tid >> 3, f4 = tid & 7;
            const int k = ks * 32 + f4 * 4;                // K=512 exact
            const float4 v = *(const float4*)(C1 + (size_t)(bm + row) * 512 + k);
            unsigned h01, l01, h23, l23;
            split_pair(v.x, v.y, h01, l01);
            split_pair(v.z, v.w, h23, l23);
            *(uint2*)(Ahs + row * 40 + f4 * 4) = make_uint2(h01, h23);
            *(uint2*)(Als + row * 40 + f4 * 4) = make_uint2(l01, l23);
        }
        __syncthreads();
        bf16x8 ah[2], al[2];
#pragma unroll
        for (int m = 0; m < 2; ++m) {
            const int off = (m * 16 + l15) * 40 + g8;
            ah[m] = *(const bf16x8*)(Ahs + off);
            al[m] = *(const bf16x8*)(Als + off);
        }
#pragma unroll
        for (int i = 0; i < 2; ++i) {
            const int nt = w + 8 * i;
            const int bo_ = ((nt * 16 + ks) << 9) + l8;
            const bf16x8 bh = *(const bf16x8*)(B2h + bo_);
            const bf16x8 bl = *(const bf16x8*)(B2l + bo_);
#pragma unroll
            for (int m = 0; m < 2; ++m) {
                acc[m][i] = __builtin_amdgcn_mfma_f32_16x16x32_bf16(ah[m], bh, acc[m][i], 0, 0, 0);
                acc[m][i] = __builtin_amdgcn_mfma_f32_16x16x32_bf16(al[m], bh, acc[m][i], 0, 0, 0);
                acc[m][i] = __builtin_amdgcn_mfma_f32_16x16x32_bf16(ah[m], bl, acc[m][i], 0, 0, 0);
            }
        }
    }
#pragma unroll
    for (int i = 0; i < 2; ++i) {
        const int col = (w + 8 * i) * 16 + l15;
        const float bj = br2[col];
#pragma unroll
        for (int m = 0; m < 2; ++m)
#pragma unroll
            for (int r = 0; r < 4; ++r) {
                const int row = m * 16 + g4 + r;
                const float v = fmaxf(acc[m][i][r] + bj, 0.f);
                unsigned short h, l; split2(v, h, l);
                Th[row * 264 + col] = h;
                Tl[row * 264 + col] = l;
            }
    }
    __syncthreads();

    // ---- stage 2: XC[:,256+] = T @ Wr3 + br3, K=256 (KS=8), N=128 (8 tiles)
    f32x4 acc2[2];
    acc2[0] = (f32x4){0.f, 0.f, 0.f, 0.f};
    acc2[1] = (f32x4){0.f, 0.f, 0.f, 0.f};
#pragma unroll
    for (int ks = 0; ks < 8; ++ks) {
        bf16x8 ah[2], al[2];
#pragma unroll
        for (int m = 0; m < 2; ++m) {
            const int off = (m * 16 + l15) * 264 + ks * 32 + g8;
            ah[m] = *(const bf16x8*)(Th + off);
            al[m] = *(const bf16x8*)(Tl + off);
        }
        const int bo_ = ((w * 8 + ks) << 9) + l8;
        const bf16x8 bh = *(const bf16x8*)(B3h + bo_);
        const bf16x8 bl = *(const bf16x8*)(B3l + bo_);
#pragma unroll
        for (int m = 0; m < 2; ++m) {
            acc2[m] = __builtin_amdgcn_mfma_f32_16x16x32_bf16(ah[m], bh, acc2[m], 0, 0, 0);
            acc2[m] = __builtin_amdgcn_mfma_f32_16x16x32_bf16(al[m], bh, acc2[m], 0, 0, 0);
            acc2[m] = __builtin_amdgcn_mfma_f32_16x16x32_bf16(ah[m], bl, acc2[m], 0, 0, 0);
        }
    }
    {
        const int col = w * 16 + l15;
        const float bj = br3[col];
#pragma unroll
        for (int m = 0; m < 2; ++m)
#pragma unroll
            for (int r = 0; r < 4; ++r) {
                const int row = bm + m * 16 + g4 + r;
                XC[(size_t)row * 384 + 256 + col] = acc2[m][r] + bj;
            }
    }
}

// ---------------------------------------------------------------------------
// Fused drug heads: XC[:,0:128 / 128:256] = (relu(G@Wg1+bg1)) @ Wg2 + bg2.
// 512 threads, 64-row blocks. Stage1: nt = w+8i (<10); stage2: nt = w.
// ---------------------------------------------------------------------------
__global__ __launch_bounds__(512) void drughead(
    const float* __restrict__ G,                           // [16384][312]
    const unsigned short* __restrict__ B1h, const unsigned short* __restrict__ B1l,
    const unsigned short* __restrict__ B2h, const unsigned short* __restrict__ B2l,
    const float* __restrict__ bg1, const float* __restrict__ bg2,
    float* __restrict__ XC)
{
    __shared__ unsigned short Ahs[64 * 40], Als[64 * 40];
    __shared__ unsigned short Th[64 * 168], Tl[64 * 168];
    const int tid = threadIdx.x, lane = tid & 63, w = tid >> 6;
    const int bm = blockIdx.x * 64;
    const int l15 = lane & 15, g8 = (lane >> 4) << 3, g4 = (lane >> 4) << 2;
    const int l8 = lane << 3;

    // ---- stage 1: T = relu(G @ Wg1 + bg1), K=312 (KS=10), N=156 (10 tiles)
    f32x4 acc[4][2];
#pragma unroll
    for (int m = 0; m < 4; ++m)
#pragma unroll
        for (int i = 0; i < 2; ++i) acc[m][i] = (f32x4){0.f, 0.f, 0.f, 0.f};
    for (int ks = 0; ks < 10; ++ks) {
        __syncthreads();
        {
            const int row = tid >> 3, f4 = tid & 7;
            const int k = ks * 32 + f4 * 4;
            const float4 v = (k < 312) ? *(const float4*)(G + (size_t)(bm + row) * 312 + k)
                                       : make_float4(0.f, 0.f, 0.f, 0.f);
            unsigned h01, l01, h23, l23;
            split_pair(v.x, v.y, h01, l01);
            split_pair(v.z, v.w, h23, l23);
            *(uint2*)(Ahs + row * 40 + f4 * 4) = make_uint2(h01, h23);
            *(uint2*)(Als + row * 40 + f4 * 4) = make_uint2(l01, l23);
        }
        __syncthreads();
        bf16x8 ah[4], al[4];
#pragma unroll
        for (int m = 0; m < 4; ++m) {
            const int off = (m * 16 + l15) * 40 + g8;
            ah[m] = *(const bf16x8*)(Ahs + off);
            al[m] = *(const bf16x8*)(Als + off);
        }
#pragma unroll
        for (int i = 0; i < 2; ++i) {
            const int nt = w + 8 * i;
            if (nt < 10) {
                const int bo = ((nt * 10 + ks) << 9) + l8;
                const bf16x8 bh = *(const bf16x8*)(B1h + bo);
                const bf16x8 bl = *(const bf16x8*)(B1l + bo);
#pragma unroll
                for (int m = 0; m < 4; ++m) {
                    acc[m][i] = __builtin_amdgcn_mfma_f32_16x16x32_bf16(ah[m], bh, acc[m][i], 0, 0, 0);
                    acc[m][i] = __builtin_amdgcn_mfma_f32_16x16x32_bf16(al[m], bh, acc[m][i], 0, 0, 0);
                    acc[m][i] = __builtin_amdgcn_mfma_f32_16x16x32_bf16(ah[m], bl, acc[m][i], 0, 0, 0);
                }
            }
        }
    }
    // epi1: relu+bias, split -> T (cols 156..159 zeroed for NaN safety)
#pragma unroll
    for (int i = 0; i < 2; ++i) {
        const int nt = w + 8 * i;
        if (nt < 10) {
            const int col = nt * 16 + l15;
            const float bj = (col < 156) ? bg1[col] : 0.f;
#pragma unroll
            for (int m = 0; m < 4; ++m)
#pragma unroll
                for (int r = 0; r < 4; ++r) {
                    const int row = m * 16 + g4 + r;
                    float v = (col < 156) ? fmaxf(acc[m][i][r] + bj, 0.f) : 0.f;
                    unsigned short h, l; split2(v, h, l);
                    Th[row * 168 + col] = h;
                    Tl[row * 168 + col] = l;
                }
        }
    }
    __syncthreads();

    // ---- stage 2: XC cols = T @ Wg2 + bg2, K=156 (KS=5), N=128 (8 tiles)
    f32x4 acc2[4];
#pragma unroll
    for (int m = 0; m < 4; ++m) acc2[m] = (f32x4){0.f, 0.f, 0.f, 0.f};
#pragma unroll
    for (int ks = 0; ks < 5; ++ks) {
        bf16x8 ah[4], al[4];
#pragma unroll
        for (int m = 0; m < 4; ++m) {
            const int off = (m * 16 + l15) * 168 + ks * 32 + g8;
            ah[m] = *(const bf16x8*)(Th + off);
            al[m] = *(const bf16x8*)(Tl + off);
        }
        const int bo = ((w * 5 + ks) << 9) + l8;
        const bf16x8 bh = *(const bf16x8*)(B2h + bo);
        const bf16x8 bl = *(const bf16x8*)(B2l + bo);
#pragma unroll
        for (int m = 0; m < 4; ++m) {
            acc2[m] = __builtin_amdgcn_mfma_f32_16x16x32_bf16(ah[m], bh, acc2[m], 0, 0, 0);
            acc2[m] = __builtin_amdgcn_mfma_f32_16x16x32_bf16(al[m], bh, acc2[m], 0, 0, 0);
            acc2[m] = __builtin_amdgcn_mfma_f32_16x16x32_bf16(ah[m], bl, acc2[m], 0, 0, 0);
        }
    }
    {
        const int col = w * 16 + l15;
        const float bj = bg2[col];
#pragma unroll
        for (int m = 0; m < 4; ++m)
#pragma unroll
            for (int r = 0; r < 4; ++r) {
                const int row = bm + m * 16 + g4 + r;
                const int crow = row & (BGRAPH - 1);
                const int cadd = (row >> 13) * 128;
                XC[(size_t)crow * 384 + cadd + col] = acc2[m][r] + bj;
            }
    }
}

// ---------------------------------------------------------------------------
// Fused head: out = (relu(relu(XC@Wf1+bf1)@Wf2+bf2)) @ Wo + bo.
// 512 threads, 32-row blocks. Stage1: nt = w+8i; stage2: nt = w; stage3 w==0.
// ---------------------------------------------------------------------------
__global__ __launch_bounds__(512) void head_fused(
    const float* __restrict__ XC,                          // [8192][384]
    const unsigned short* __restrict__ B1h, const unsigned short* __restrict__ B1l,
    const unsigned short* __restrict__ B2h, const unsigned short* __restrict__ B2l,
    const unsigned short* __restrict__ B3h, const unsigned short* __restrict__ B3l,
    const float* __restrict__ bf1, const float* __restrict__ bf2, const float* __restrict__ bo,
    float* __restrict__ out)
{
    __shared__ unsigned short Ahs[32 * 40], Als[32 * 40];
    __shared__ unsigned short T1h[32 * 280], T1l[32 * 280];
    unsigned short* T2h = T1h;                             // aliased, stride 136
    unsigned short* T2l = T1l;
    const int tid = threadIdx.x, lane = tid & 63, w = tid >> 6;
    const int bm = blockIdx.x * 32;
    const int l15 = lane & 15, g8 = (lane >> 4) << 3, g4 = (lane >> 4) << 2;
    const int l8 = lane << 3;

    // ---- stage 1: T1 = relu(XC @ Wf1 + bf1), K=384 (KS=12), N=256 (16 tiles)
    f32x4 acc[2][2];
#pragma unroll
    for (int m = 0; m < 2; ++m)
#pragma unroll
        for (int i = 0; i < 2; ++i) acc[m][i] = (f32x4){0.f, 0.f, 0.f, 0.f};
    for (int ks = 0; ks < 12; ++ks) {
        __syncthreads();
        if (tid < 256) {
            const int row = tid >> 3, f4 = tid & 7;
            const int k = ks * 32 + f4 * 4;                // K=384 exact
            const float4 v = *(const float4*)(XC + (size_t)(bm + row) * 384 + k);
            unsigned h01, l01, h23, l23;
            split_pair(v.x, v.y, h01, l01);
            split_pair(v.z, v.w, h23, l23);
            *(uint2*)(Ahs + row * 40 + f4 * 4) = make_uint2(h01, h23);
            *(uint2*)(Als + row * 40 + f4 * 4) = make_uint2(l01, l23);
        }
        __syncthreads();
        bf16x8 ah[2], al[2];
#pragma unroll
        for (int m = 0; m < 2; ++m) {
            const int off = (m * 16 + l15) * 40 + g8;
            ah[m] = *(const bf16x8*)(Ahs + off);
            al[m] = *(const bf16x8*)(Als + off);
        }
#pragma unroll
        for (int i = 0; i < 2; ++i) {
            const int nt = w + 8 * i;
            const int bo_ = ((nt * 12 + ks) << 9) + l8;
            const bf16x8 bh = *(const bf16x8*)(B1h + bo_);
            const bf16x8 bl = *(const bf16x8*)(B1l + bo_);
#pragma unroll
            for (int m = 0; m < 2; ++m) {
                acc[m][i] = __builtin_amdgcn_mfma_f32_16x16x32_bf16(ah[m], bh, acc[m][i], 0, 0, 0);
                acc[m][i] = __builtin_amdgcn_mfma_f32_16x16x32_bf16(al[m], bh, acc[m][i], 0, 0, 0);
                acc[m][i] = __builtin_amdgcn_mfma_f32_16x16x32_bf16(ah[m], bl, acc[m][i], 0, 0, 0);
            }
        }
    }
#pragma unroll
    for (int i = 0; i < 2; ++i) {
        const int col = (w + 8 * i) * 16 + l15;
        const float bj = bf1[col];
#pragma unroll
        for (int m = 0; m < 2; ++m)
#pragma unroll
            for (int r = 0; r < 4; ++r) {
                const int row = m * 16 + g4 + r;
                const float v = fmaxf(acc[m][i][r] + bj, 0.f);
                unsigned short h, l; split2(v, h, l);
                T1h[row * 280 + col] = h;
                T1l[row * 280 + col] = l;
            }
    }
    __syncthreads();

    // ---- stage 2: T2 = relu(T1 @ Wf2 + bf2), K=256 (KS=8), N=128 (8 tiles)
    f32x4 acc2[2];
    acc2[0] = (f32x4){0.f, 0.f, 0.f, 0.f};
    acc2[1] = (f32x4){0.f, 0.f, 0.f, 0.f};
#pragma unroll
    for (int ks = 0; ks < 8; ++ks) {
        bf16x8 ah[2], al[2];
#pragma unroll
        for (int m = 0; m < 2; ++m) {
            const int off = (m * 16 + l15) * 280 + ks * 32 + g8;
            ah[m] = *(const bf16x8*)(T1h + off);
            al[m] = *(const bf16x8*)(T1l + off);
        }
        const int bo_ = ((w * 8 + ks) << 9) + l8;
        const bf16x8 bh = *(const bf16x8*)(B2h + bo_);
        const bf16x8 bl = *(const bf16x8*)(B2l + bo_);
#pragma unroll
        for (int m = 0; m < 2; ++m) {
            acc2[m] = __builtin_amdgcn_mfma_f32_16x16x32_bf16(ah[m], bh, acc2[m], 0, 0, 0);
            acc2[m] = __builtin_amdgcn_mfma_f32_16x16x32_bf16(al[m], bh, acc2[m], 0, 0, 0);
            acc2[m] = __builtin_amdgcn_mfma_f32_16x16x32_bf16(ah[m], bl, acc2[m], 0, 0, 0);
        }
    }
    __syncthreads();                       // all T1 reads done (T2 aliases T1)
    {
        const int col = w * 16 + l15;
        const float bj = bf2[col];
#pragma unroll
        for (int m = 0; m < 2; ++m)
#pragma unroll
            for (int r = 0; r < 4; ++r) {
                const int row = m * 16 + g4 + r;
                const float v = fmaxf(acc2[m][r] + bj, 0.f);
                unsigned short h, l; split2(v, h, l);
                T2h[row * 136 + col] = h;
                T2l[row * 136 + col] = l;
            }
    }
    __syncthreads();

    // ---- stage 3: out = T2 @ Wo + bo, K=128 (KS=4), N=2 (tile 0, wave 0)
    if (w == 0) {
        f32x4 acc3[2];
        acc3[0] = (f32x4){0.f, 0.f, 0.f, 0.f};
        acc3[1] = (f32x4){0.f, 0.f, 0.f, 0.f};
#pragma unroll
        for (int ks = 0; ks < 4; ++ks) {
            bf16x8 ah[2], al[2];
#pragma unroll
            for (int m = 0; m < 2; ++m) {
                const int off = (m * 16 + l15) * 136 + ks * 32 + g8;
                ah[m] = *(const bf16x8*)(T2h + off);
                al[m] = *(const bf16x8*)(T2l + off);
            }
            const int bo_ = (ks << 9) + l8;
            const bf16x8 bh = *(const bf16x8*)(B3h + bo_);
            const bf16x8 bl = *(const bf16x8*)(B3l + bo_);
#pragma unroll
            for (int m = 0; m < 2; ++m) {
                acc3[m] = __builtin_amdgcn_mfma_f32_16x16x32_bf16(ah[m], bh, acc3[m], 0, 0, 0);
                acc3[m] = __builtin_amdgcn_mfma_f32_16x16x32_bf16(al[m], bh, acc3[m], 0, 0, 0);
                acc3[m] = __builtin_amdgcn_mfma_f32_16x16x32_bf16(ah[m], bl, acc3[m], 0, 0, 0);
            }
        }
        if (l15 < 2) {
            const float bj = bo[l15];
#pragma unroll
            for (int m = 0; m < 2; ++m)
#pragma unroll
                for (int r = 0; r < 4; ++r)
                    out[(size_t)(bm + m * 16 + g4 + r) * 2 + l15] = acc3[m][r] + bj;
        }
    }
}

// ---------------------------------------------------------------------------

extern "C" void kernel_launch(void* const* d_in, const int* in_sizes, int n_in,
                              void* d_out, int out_size, void* d_ws, size_t ws_size,
                              hipStream_t stream)
{
    (void)in_sizes; (void)n_in; (void)out_size; (void)ws_size;
    const float* x1   = (const float*)d_in[0];
    const int*   ei1  = (const int*)d_in[1];
    const float* x2   = (const float*)d_in[3];
    const int*   ei2  = (const int*)d_in[4];
    const float* cell = (const float*)d_in[6];
    const float* Wc1 = (const float*)d_in[7],  *bc1 = (const float*)d_in[8];
    const float* Wc2 = (const float*)d_in[9],  *bc2 = (const float*)d_in[10];
    const float* Wc3 = (const float*)d_in[11], *bc3 = (const float*)d_in[12];
    const float* Wg1 = (const float*)d_in[13], *bg1 = (const float*)d_in[14];
    const float* Wg2 = (const float*)d_in[15], *bg2 = (const float*)d_in[16];
    const float* Wr1 = (const float*)d_in[17], *br1 = (const float*)d_in[18];
    const float* Wr2 = (const float*)d_in[19], *br2 = (const float*)d_in[20];
    const float* Wr3 = (const float*)d_in[21], *br3 = (const float*)d_in[22];
    const float* Wf1 = (const float*)d_in[23], *bf1 = (const float*)d_in[24];
    const float* Wf2 = (const float*)d_in[25], *bf2 = (const float*)d_in[26];
    const float* Wo  = (const float*)d_in[27], *bo  = (const float*)d_in[28];
    float* out = (float*)d_out;
    float* ws  = (float*)d_ws;

    size_t o = 0;
    auto allocF = [&](size_t n) { float* p = ws + o; o += n; return p; };
    auto allocU = [&](size_t n) { unsigned short* p = (unsigned short*)(ws + o); o += n / 2; return p; };

    float* G1  = allocF((size_t)2 * BGRAPH * 312);   // both branches stacked
    float* C1  = allocF((size_t)BGRAPH * 512);
    float* XC  = allocF((size_t)BGRAPH * 384);

    // swizzled split weights (ushort counts = NT*KS*512)
    const int sWc1 = 8  * 3  * 512, sWc2 = 12 * 3  * 512, sWc3 = 20 * 5  * 512;
    const int sWg1 = 10 * 10 * 512, sWg2 = 8  * 5  * 512;
    const int sWr1 = 32 * 30 * 512, sWr2 = 16 * 16 * 512, sWr3 = 8 * 8 * 512;
    const int sWf1 = 16 * 12 * 512, sWf2 = 8  * 8  * 512, sWoo = 1 * 4 * 512;
    unsigned short *Wc1h = allocU(sWc1), *Wc1l = allocU(sWc1);
    unsigned short *Wc2h = allocU(sWc2), *Wc2l = allocU(sWc2);
    unsigned short *Wc3h = allocU(sWc3), *Wc3l = allocU(sWc3);
    unsigned short *Wg1h = allocU(sWg1), *Wg1l = allocU(sWg1);
    unsigned short *Wg2h = allocU(sWg2), *Wg2l = allocU(sWg2);
    unsigned short *Wr1h = allocU(sWr1), *Wr1l = allocU(sWr1);
    unsigned short *Wr2h = allocU(sWr2), *Wr2l = allocU(sWr2);
    unsigned short *Wr3h = allocU(sWr3), *Wr3l = allocU(sWr3);
    unsigned short *Wf1h = allocU(sWf1), *Wf1l = allocU(sWf1);
    unsigned short *Wf2h = allocU(sWf2), *Wf2l = allocU(sWf2);
    unsigned short *Wooh = allocU(sWoo), *Wool = allocU(sWoo);

    // one fused weight-prep launch
    WTab tab;
    int base = 0, ti = 0;
    auto addw = [&](const float* W, int K, int N, int KS, int NT,
                    unsigned short* Bh, unsigned short* Bl) {
        tab.d[ti] = WDesc{W, Bh, Bl, K, N, KS, NT, base};
        base += NT * KS * 2;              // blocks = NT*KS*512/256
        ++ti;
    };
    addw(Wc1, 78, 78, 3, 8, Wc1h, Wc1l);
    addw(Wc2, 78, 156, 3, 12, Wc2h, Wc2l);
    addw(Wc3, 156, 312, 5, 20, Wc3h, Wc3l);
    addw(Wg1, 312, 156, 10, 10, Wg1h, Wg1l);
    addw(Wg2, 156, 128, 5, 8, Wg2h, Wg2l);
    addw(Wr1, 954, 512, 30, 32, Wr1h, Wr1l);
    addw(Wr2, 512, 256, 16, 16, Wr2h, Wr2l);
    addw(Wr3, 256, 128, 8, 8, Wr3h, Wr3l);
    addw(Wf1, 384, 256, 12, 16, Wf1h, Wf1l);
    addw(Wf2, 256, 128, 8, 8, Wf2h, Wf2l);
    addw(Wo,  128, 2,   4, 1, Wooh, Wool);
    wprep_all<<<base, 256, 0, stream>>>(tab);

    // both drug branches (GCN x3 + maxpool) in one launch; G2 follows G1
    gcn_graph<<<2 * BGRAPH, GT, 0, stream>>>(x1, ei1, x2, ei2,
        Wc1h, Wc1l, Wc2h, Wc2l, Wc3h, Wc3l, bc1, bc2, bc3, G1);

    // fused drug heads (M = 16384): G -> XC[:,0:128] / [:,128:256]
    drughead<<<256, 512, 0, stream>>>(G1, Wg1h, Wg1l, Wg2h, Wg2l, bg1, bg2, XC);

    // cell MLP -> XC[:,256:384] (stage 1 fuses the L2 normalize; 2+3 fused)
    cell_s1<<<dim3(128, 2), 512, 0, stream>>>(cell, Wr1h, Wr1l, br1, C1);
    cell_s23<<<256, 512, 0, stream>>>(C1, Wr2h, Wr2l, Wr3h, Wr3l, br2, br3, XC);

    // fused head: XC -> out
    head_fused<<<256, 512, 0, stream>>>(XC, Wf1h, Wf1l, Wf2h, Wf2l, Wooh, Wool,
                                        bf1, bf2, bo, out);
}